// Round 21
// baseline (2884.712 us; speedup 1.0000x reference)
//
#include <hip/hip_runtime.h>
#include <math.h>

#define NN 716
#define NSQ (716*716)
#define MAXG 9216
#define FPAD 70
#define XPAD 102
typedef unsigned short bfu;
typedef __attribute__((ext_vector_type(8))) __bf16 bf16x8;
typedef __attribute__((ext_vector_type(4))) float f32x4;

__device__ __forceinline__ float b2f(bfu u){ union{unsigned int i; float f;} x; x.i = ((unsigned int)u)<<16; return x.f; }
__device__ __forceinline__ bfu f2b(float f){ union{float fv; unsigned int i;} x; x.fv = f; unsigned int r = (x.i + 0x7fffu + ((x.i>>16)&1u)) >> 16; return (bfu)r; }
__device__ __forceinline__ float sigmoidf_(float x){ return 1.f/(1.f+expf(-x)); }

__device__ __forceinline__ float fexp_(float x){
#if __has_builtin(__builtin_amdgcn_exp2f)
  return __builtin_amdgcn_exp2f(x * 1.44269504088896340736f);
#else
  return __expf(x);
#endif
}
__device__ __forceinline__ float frcp_(float x){
#if __has_builtin(__builtin_amdgcn_rcpf)
  return __builtin_amdgcn_rcpf(x);
#else
  return 1.f/x;
#endif
}
__device__ __forceinline__ float fsig_(float x){ return frcp_(1.f + fexp_(-x)); }
__device__ __forceinline__ float ftanh_(float x){
  float xc = fminf(fmaxf(x, -30.f), 30.f);
  float e = fexp_(-2.f*xc);
  return (1.f - e) * frcp_(1.f + e);
}

// ---------------- init / adjacency construction ----------------

__global__ void k_ind(const float* __restrict__ hist, int* __restrict__ ind){
  int b = threadIdx.x; if (b >= 64) return;
  float v = hist[((b*12+11)*NN + 0)*2 + 1];
  ind[b] = ((int)(v*288.0f)) % 288;
}

__global__ void k_dg1(const float* __restrict__ p1, const float* __restrict__ pk,
                      const int* __restrict__ ind, float* __restrict__ tmp1){
  int b = blockIdx.x;
  __shared__ float p1s[40];
  if (threadIdx.x < 40) p1s[threadIdx.x] = p1[ind[b]*40 + threadIdx.x];
  __syncthreads();
  for (int jk = threadIdx.x; jk < 1600; jk += 256){
    float acc = 0.f;
    for (int i = 0; i < 40; ++i) acc += p1s[i]*pk[i*1600 + jk];
    tmp1[b*1600 + jk] = acc;
  }
}

__global__ void k_dg2(const float* __restrict__ p2, const float* __restrict__ tmp1,
                      float* __restrict__ tmp2){
  int b = blockIdx.y;
  __shared__ float ts[1600];
  for (int i = threadIdx.x; i < 1600; i += 256) ts[i] = tmp1[b*1600+i];
  __syncthreads();
  int idx = blockIdx.x*256 + threadIdx.x;
  if (idx >= NN*40) return;
  int n = idx/40, k = idx%40;
  float acc = 0.f;
  for (int j = 0; j < 40; ++j) acc += p2[n*40+j]*ts[j*40+k];
  tmp2[(long)b*NN*40 + idx] = acc;
}

__global__ void k_p3t(const float* __restrict__ p3, float* __restrict__ p3t){
  int v = blockIdx.x*256 + threadIdx.x; if (v >= NN) return;
  for (int k = 0; k < 40; ++k) p3t[k*NN + v] = p3[v*40 + k];
}

// 4 adjacency rows per block: logits -> relu -> softmax -> SPARSE top-16 capture
__global__ __launch_bounds__(256) void k_adjrow4s(const float* __restrict__ p3t,
    const float* __restrict__ tmp2, unsigned int* __restrict__ topA,
    int* __restrict__ cntA)
{
  int b = blockIdx.y, w0 = blockIdx.x*4, tid = threadIdx.x;
  int wave = tid >> 6, lane = tid & 63;
  __shared__ float t2s[4][40];
  __shared__ float buf[4][720];
  __shared__ float wred[4][4];
  __shared__ float rstat[4];
  __shared__ int pc[4][12];
  for (int i = tid; i < 160; i += 256){
    int r = i/40, k = i%40; int w = w0 + r;
    t2s[r][k] = (w < NN) ? tmp2[((long)b*NN + w)*40 + k] : 0.f;
  }
  __syncthreads();
  float lmax[4] = {0,0,0,0};
  for (int q = 0; q < 3; ++q){
    int v = tid + q*256;
    if (v < NN){
      float a[4] = {0,0,0,0};
      #pragma unroll 8
      for (int k = 0; k < 40; ++k){
        float pv = p3t[k*NN + v];
        #pragma unroll
        for (int r = 0; r < 4; ++r) a[r] += t2s[r][k]*pv;
      }
      #pragma unroll
      for (int r = 0; r < 4; ++r){
        float val = fmaxf(a[r], 0.f);
        buf[r][v] = val;
        lmax[r] = fmaxf(lmax[r], val);
      }
    }
  }
  #pragma unroll
  for (int r = 0; r < 4; ++r){
    float m = lmax[r];
    for (int s = 32; s > 0; s >>= 1) m = fmaxf(m, __shfl_xor(m, s, 64));
    if (lane == 0) wred[r][wave] = m;
  }
  __syncthreads();
  if (tid < 4) rstat[tid] = fmaxf(fmaxf(wred[tid][0], wred[tid][1]), fmaxf(wred[tid][2], wred[tid][3]));
  __syncthreads();
  float lsum[4] = {0,0,0,0};
  for (int q = 0; q < 3; ++q){
    int v = tid + q*256;
    if (v < NN){
      #pragma unroll
      for (int r = 0; r < 4; ++r){
        float e = fexp_(buf[r][v] - rstat[r]);
        buf[r][v] = e;
        lsum[r] += e;
      }
    }
  }
  __syncthreads();
  #pragma unroll
  for (int r = 0; r < 4; ++r){
    float s = lsum[r];
    for (int k = 32; k > 0; k >>= 1) s += __shfl_xor(s, k, 64);
    if (lane == 0) wred[r][wave] = s;
  }
  __syncthreads();
  if (tid < 4) rstat[tid] = frcp_(wred[tid][0] + wred[tid][1] + wred[tid][2] + wred[tid][3]);
  __syncthreads();
  for (int q = 0; q < 3; ++q){
    int v = tid + q*256;
    #pragma unroll
    for (int r = 0; r < 4; ++r){
      float p = (v < NN) ? buf[r][v]*rstat[r] : 0.f;
      unsigned long long m = __ballot(p >= 1e-7f);
      if (lane == 0) pc[r][q*4+wave] = __popcll(m);
    }
  }
  __syncthreads();
  for (int q = 0; q < 3; ++q){
    int v = tid + q*256;
    #pragma unroll
    for (int r = 0; r < 4; ++r){
      float p = (v < NN) ? buf[r][v]*rstat[r] : 0.f;
      bool qual = (p >= 1e-7f);
      unsigned long long m = __ballot(qual);
      int w = w0 + r;
      if (qual && w < NN){
        int base = 0, me = q*4+wave;
        for (int s = 0; s < me; ++s) base += pc[r][s];
        unsigned long long below = (lane == 0) ? 0ull : (m << (64-lane) >> (64-lane));
        int pos = base + __popcll(below);
        if (pos < 16)
          topA[((long)b*NN + w)*16 + pos] = (((unsigned)v)<<16) | (unsigned)f2b(p);
      }
    }
  }
  __syncthreads();
  if (tid < 4){
    int w = w0 + tid;
    if (w < NN){
      int tot = 0;
      for (int s = 0; s < 12; ++s) tot += pc[tid][s];
      cntA[(long)b*NN + w] = (tot < 16) ? tot : 16;
    }
  }
}

// fused double sparse diffusion: z1[m] = A-gather(X[m]); z2[m] = A-gather(z1[m])
// gather lists loaded as uint4 (4 entries / load, cnt-guarded, same accum order)
__global__ __launch_bounds__(256) void k_zgather2(const bfu* __restrict__ Xg,
    const unsigned int* __restrict__ topA, const int* __restrict__ cntA,
    bfu* __restrict__ Z1g, bfu* __restrict__ Z2g, int M, long sx)
{
  __shared__ bfu rows[4][720];
  __shared__ bfu zrow[4][720];
  int b = blockIdx.y;
  int tid = threadIdx.x, wave = tid >> 6, lane = tid & 63;
  int m = blockIdx.x*4 + wave;
  if (m < M){
    const bfu* xr = Xg + (long)b*sx + (long)m*NN;
    #pragma unroll
    for (int q = 0; q < 12; ++q){
      int v = lane + q*64;
      if (v < NN) rows[wave][v] = xr[v];
    }
  }
  __syncthreads();
  const unsigned int* ta = topA + (long)b*NN*16;
  const int* ca = cntA + (long)b*NN;
  if (m < M){
    bfu* zr = Z1g + (long)b*sx + (long)m*NN;
    #pragma unroll
    for (int q = 0; q < 12; ++q){
      int w = lane + q*64;
      if (w < NN){
        int cnt = ca[w];
        const unsigned int* lst = ta + (long)w*16;
        float acc = 0.f;
        for (int j4 = 0; j4 < 16 && j4 < cnt; j4 += 4){
          uint4 e4 = *(const uint4*)(lst + j4);
          if (j4+0 < cnt) acc += b2f((bfu)(e4.x & 0xffffu)) * b2f(rows[wave][e4.x >> 16]);
          if (j4+1 < cnt) acc += b2f((bfu)(e4.y & 0xffffu)) * b2f(rows[wave][e4.y >> 16]);
          if (j4+2 < cnt) acc += b2f((bfu)(e4.z & 0xffffu)) * b2f(rows[wave][e4.z >> 16]);
          if (j4+3 < cnt) acc += b2f((bfu)(e4.w & 0xffffu)) * b2f(rows[wave][e4.w >> 16]);
        }
        bfu zv = f2b(acc);
        zr[w] = zv;
        zrow[wave][w] = zv;
      }
    }
  }
  __syncthreads();
  if (m >= M) return;
  bfu* z2r = Z2g + (long)b*sx + (long)m*NN;
  #pragma unroll
  for (int q = 0; q < 12; ++q){
    int w = lane + q*64;
    if (w < NN){
      int cnt = ca[w];
      const unsigned int* lst = ta + (long)w*16;
      float acc = 0.f;
      for (int j4 = 0; j4 < 16 && j4 < cnt; j4 += 4){
        uint4 e4 = *(const uint4*)(lst + j4);
        if (j4+0 < cnt) acc += b2f((bfu)(e4.x & 0xffffu)) * b2f(zrow[wave][e4.x >> 16]);
        if (j4+1 < cnt) acc += b2f((bfu)(e4.y & 0xffffu)) * b2f(zrow[wave][e4.y >> 16]);
        if (j4+2 < cnt) acc += b2f((bfu)(e4.z & 0xffffu)) * b2f(zrow[wave][e4.z >> 16]);
        if (j4+3 < cnt) acc += b2f((bfu)(e4.w & 0xffffu)) * b2f(zrow[wave][e4.w >> 16]);
      }
      z2r[w] = f2b(acc);
    }
  }
}

// xs[n][t] = sum_b x_a[b,n,t]; y[n] = sum_t xs[n][t]
__global__ void k_xs(const float* __restrict__ hist, const float* __restrict__ saW,
                     const float* __restrict__ sab, float* __restrict__ xs, float* __restrict__ y){
  int n = blockIdx.x, b = threadIdx.x; // 64 threads
  float w = saW[0], bb = sab[0];
  float ytot = 0.f;
  for (int t = 0; t < 13; ++t){
    float inp = (t == 0) ? 0.f : hist[((b*12 + (t-1))*NN + n)*2];
    float s = inp;
    for (int off = 32; off > 0; off >>= 1) s += __shfl_down(s, off, 64);
    if (b == 0){ float val = w*s + 64.f*bb; xs[n*13+t] = val; ytot += val; }
  }
  if (b == 0) y[n] = ytot;
}

__global__ void k_adjp(const float* __restrict__ xs, const float* __restrict__ y,
                       const float* __restrict__ piv, float* __restrict__ adjp){
  int i = blockIdx.y;
  __shared__ float xi[13];
  if (threadIdx.x < 13) xi[threadIdx.x] = xs[i*13+threadIdx.x];
  __syncthreads();
  int j = blockIdx.x*256 + threadIdx.x;
  if (j >= NN) return;
  float acc = 0.f;
  #pragma unroll
  for (int t = 0; t < 12; ++t) acc += xi[t]*xs[j*13+t+1];
  adjp[(long)i*NN+j] = acc / y[j] * piv[(long)i*NN+j];
}

__global__ void k_score(const float* __restrict__ adjp, float* __restrict__ score){
  int n = blockIdx.x, tid = threadIdx.x;
  float s = 0.f;
  for (int i = tid; i < NN; i += 256) s += adjp[(long)i*NN+n] + adjp[(long)n*NN+i];
  __shared__ float red[256];
  red[tid] = s; __syncthreads();
  for (int k = 128; k > 0; k >>= 1){ if (tid < k) red[tid] += red[tid+k]; __syncthreads(); }
  if (tid == 0) score[n] = red[0];
}

// bitonic sort 1024 (desc, tie->lower index first), take top 100 -> mask
__global__ void k_topk(const float* __restrict__ score, int* __restrict__ mask){
  __shared__ float v[1024];
  __shared__ int ix[1024];
  int tid = threadIdx.x;
  for (int t = tid; t < 1024; t += 256){ v[t] = (t < NN) ? score[t] : -INFINITY; ix[t] = t; }
  __syncthreads();
  for (int k = 2; k <= 1024; k <<= 1){
    for (int j = k >> 1; j > 0; j >>= 1){
      for (int t = tid; t < 1024; t += 256){
        int l = t ^ j;
        if (l > t){
          bool up = ((t & k) == 0);
          bool g = (v[t] > v[l]) || (v[t] == v[l] && ix[t] < ix[l]);
          if (up ? !g : g){
            float tv = v[t]; v[t] = v[l]; v[l] = tv;
            int ti = ix[t]; ix[t] = ix[l]; ix[l] = ti;
          }
        }
      }
      __syncthreads();
    }
  }
  for (int t = tid; t < NN; t += 256) mask[t] = 0;
  __syncthreads();
  if (tid < 100) mask[ix[tid]] = 1;
}

// build compact pivotal structure: idx[100], rank[716], u[100], ApkR[100r][100k]
__global__ void k_pivprep(const float* __restrict__ adjp, const int* __restrict__ mask,
                          int* __restrict__ idxk, int* __restrict__ rankv,
                          float* __restrict__ uvec, float* __restrict__ ApkR){
  __shared__ int sidx[100];
  int tid = threadIdx.x;
  if (tid == 0){
    int c = 0;
    for (int i = 0; i < NN; ++i){
      if (mask[i] && c < 100){ sidx[c] = i; idxk[c] = i; rankv[i] = c; ++c; }
      else rankv[i] = -1;
    }
  }
  __syncthreads();
  if (tid < 100){
    int i = sidx[tid];
    const float* row = adjp + (long)i*NN;
    float mx = 0.f;
    for (int k = 0; k < 100; ++k) mx = fmaxf(mx, row[sidx[k]]);
    float sum = 616.f * fexp_(-mx);
    for (int k = 0; k < 100; ++k) sum += fexp_(fmaxf(row[sidx[k]], 0.f) - mx);
    float inv = 1.f/sum;
    uvec[tid] = fexp_(-mx)*inv;
    // row-major per output index r=tid: ApkR[r][k] = softmax weight of input k
    for (int k = 0; k < 100; ++k)
      ApkR[tid*100 + k] = fexp_(fmaxf(row[sidx[k]], 0.f) - mx)*inv;
  }
}

// x[b,c,t,n] = start_W[c]*inp + start_b[c]
__global__ void k_init_x(const float* __restrict__ hist, const float* __restrict__ sW,
                         const float* __restrict__ sb, bfu* __restrict__ x){
  int n = blockIdx.x*256 + threadIdx.x; if (n >= NN) return;
  int t = blockIdx.y, b = blockIdx.z;
  float inp = (t == 0) ? 0.f : hist[((b*12 + (t-1))*NN + n)*2];
  #pragma unroll
  for (int c = 0; c < 32; ++c)
    x[((long)(b*32+c)*13 + t)*NN + n] = f2b(sW[c]*inp + sb[c]);
}

// identity BN params
__global__ void k_bnid(float* __restrict__ bnp){
  int c = threadIdx.x; if (c >= 32) return;
  bnp[c*2] = 1.f; bnp[c*2+1] = 0.f;
}

// permuted e1W -> bf16
__global__ void k_e1perm(const float* __restrict__ W, bfu* __restrict__ Wb){
  int i = blockIdx.x*256 + threadIdx.x;
  if (i >= 512*416) return;
  int e = i/416, kp = i%416;
  const int off2[9] = {0,96,176,248,304,352,384,408,416};
  const int soff[8] = {320,240,168,112,64,32,8,0};
  const int tpl[8]  = {12,10,9,7,6,4,3,1};
  int L = 0;
  #pragma unroll
  for (int q = 0; q < 8; ++q) if (kp >= off2[q+1]) L = q+1;
  int r = kp - off2[L]; int t = r>>3, sc = r&7;
  int k = soff[L] + sc*tpl[L] + t;
  Wb[e*416+kp] = f2b(W[e*416+k]);
}

// ---------------- MFMA GEMM (end1 only) ----------------
#define LDST 44

__global__ __launch_bounds__(256) void gemm_mfma(const bfu* __restrict__ Xg,
    const bfu* __restrict__ Ag, bfu* __restrict__ Cg,
    int M, int K, long sx, long sa, long sc,
    const float* __restrict__ bias, int relu_out, int Trow, int Tcomp)
{
  int bx = gridDim.x, by = gridDim.y, nb = gridDim.z;
  int bX = blockIdx.x, bY = blockIdx.y, bZ = blockIdx.z;
  int bpb = bx*by, total = bpb*nb;
  if ((total & 7) == 0 && (nb & 7) == 0){
    int L = bX + bx*(bY + by*bZ);
    int xcd = L & 7, slot = L >> 3;
    bZ = xcd*(nb >> 3) + slot/bpb;
    int inner = slot % bpb;
    bX = inner % bx; bY = inner / bx;
  }
  const bfu* X = Xg + (long)bZ*sx;
  const bfu* A = Ag + (long)bZ*sa;
  bfu*       C = Cg + (long)bZ*sc;
  int m0 = bY*128, n0 = bX*128;
  __shared__ bfu Xs[128*LDST];
  __shared__ bfu As[128*LDST];
  int tid = threadIdx.x;
  int wave = tid >> 6, lane = tid & 63;
  int wm = (wave >> 1)*64, wn = (wave & 1)*64;
  int lr = lane & 15, lg = lane >> 4;
  f32x4 acc[4][4] = {};
  int ldr = tid >> 1, ldk = (tid & 1)*16;
  int mg = m0 + ldr, ng = n0 + ldr;
  int mrow = (Trow == Tcomp) ? mg : (mg/Tcomp)*Trow + (mg%Tcomp);
  const bfu* xrow = X + (long)mrow*K;
  const bfu* arow = A + (long)ng*K;
  for (int k0 = 0; k0 < K; k0 += 32){
    int kk = k0 + ldk;
    ushort4 z4 = {0,0,0,0};
    ushort4 x0=z4,x1=z4,x2=z4,x3=z4, a0=z4,a1=z4,a2=z4,a3=z4;
    if (mg < M){
      if (kk + 16 <= K){
        const ushort4* s = (const ushort4*)(xrow + kk);
        x0=s[0]; x1=s[1]; x2=s[2]; x3=s[3];
      } else {
        bfu tv[16];
        #pragma unroll
        for (int j=0;j<16;++j) tv[j] = (kk+j < K) ? xrow[kk+j] : (bfu)0;
        const ushort4* s = (const ushort4*)tv;
        x0=s[0]; x1=s[1]; x2=s[2]; x3=s[3];
      }
    }
    if (ng < NN){
      if (kk + 16 <= K){
        const ushort4* s = (const ushort4*)(arow + kk);
        a0=s[0]; a1=s[1]; a2=s[2]; a3=s[3];
      } else {
        bfu tv[16];
        #pragma unroll
        for (int j=0;j<16;++j) tv[j] = (kk+j < K) ? arow[kk+j] : (bfu)0;
        const ushort4* s = (const ushort4*)tv;
        a0=s[0]; a1=s[1]; a2=s[2]; a3=s[3];
      }
    }
    ushort4* xd = (ushort4*)&Xs[ldr*LDST + ldk];
    xd[0]=x0; xd[1]=x1; xd[2]=x2; xd[3]=x3;
    ushort4* ad = (ushort4*)&As[ldr*LDST + ldk];
    ad[0]=a0; ad[1]=a1; ad[2]=a2; ad[3]=a3;
    __syncthreads();
    bf16x8 af[4], bfr[4];
    #pragma unroll
    for (int i=0;i<4;++i){
      af[i]  = *(const bf16x8*)&Xs[(wm + i*16 + lr)*LDST + lg*8];
      bfr[i] = *(const bf16x8*)&As[(wn + i*16 + lr)*LDST + lg*8];
    }
    #pragma unroll
    for (int i=0;i<4;++i)
      #pragma unroll
      for (int j=0;j<4;++j)
        acc[i][j] = __builtin_amdgcn_mfma_f32_16x16x32_bf16(af[i], bfr[j], acc[i][j], 0,0,0);
    __syncthreads();
  }
  #pragma unroll
  for (int i=0;i<4;++i){
    #pragma unroll
    for (int r=0;r<4;++r){
      int m = m0 + wm + i*16 + lg*4 + r;
      if (m >= M) continue;
      float bv = bias ? bias[m] : 0.f;
      #pragma unroll
      for (int j=0;j<4;++j){
        int n = n0 + wn + j*16 + lr;
        if (n < NN){
          float v = acc[i][j][r] + bv;
          if (relu_out) v = fmaxf(v, 0.f);
          C[(long)m*NN + n] = f2b(v);
        }
      }
    }
  }
}

// ---------------- MFMA gated temporal conv (128 n / block, XCD-grouped, BN-folded in-block) ----------------
__global__ __launch_bounds__(256) void k_fg_mfma(const bfu* __restrict__ x,
    const float* __restrict__ fWl, const float* __restrict__ fbl,
    const float* __restrict__ gWl, const float* __restrict__ gbl,
    const float* __restrict__ bnp, bfu* __restrict__ fg, int T, int Tp, int d)
{
  __shared__ bfu Bsh[128*FPAD];
  __shared__ bfu Ash[64*FPAD];
  __shared__ float bsh[64];
  int tid = threadIdx.x;
  int tot6 = 6*Tp;
  int L = blockIdx.x + 6*(blockIdx.y + Tp*blockIdx.z);
  int xcd = L & 7, slot = L >> 3;
  int b = xcd + ((slot/tot6) << 3);
  int r6 = slot - (slot/tot6)*tot6;
  int t = r6/6, nb6 = r6 - (r6/6)*6;
  int n0 = nb6*128;
  // weight staging with BN fold computed in-block
  for (int i = tid; i < 4096; i += 256){
    int row = i >> 6, k = i & 63;
    int o = row >> 1, isg = row & 1;
    int tap = k >> 5, c = k & 31;
    const float* W = isg ? gWl : fWl;
    Ash[row*FPAD + k] = f2b(W[(o*32+c)*2 + tap] * bnp[c*2]);
  }
  if (tid < 64){
    int o = tid >> 1, isg = tid & 1;
    const float* W = isg ? gWl : fWl;
    const float* B = isg ? gbl : fbl;
    float s = B[o];
    for (int c = 0; c < 32; ++c)
      s += (W[(o*32+c)*2] + W[(o*32+c)*2+1]) * bnp[c*2+1];
    bsh[tid] = s;
  }
  #pragma unroll
  for (int i = 0; i < 8; ++i){
    int idx = tid + i*256;
    int n4 = (idx & 31)*4;
    int cc = idx >> 5;
    int c = cc & 31, tap = cc >> 5;
    long base = ((long)(b*32+c)*T + t + (tap ? d : 0))*NN + n0 + n4;
    ushort4 v = {0,0,0,0};
    if (n0 + n4 < NN) v = *(const ushort4*)(x + base);
    Bsh[(n4+0)*FPAD + cc] = v.x;
    Bsh[(n4+1)*FPAD + cc] = v.y;
    Bsh[(n4+2)*FPAD + cc] = v.z;
    Bsh[(n4+3)*FPAD + cc] = v.w;
  }
  __syncthreads();
  int wave = tid >> 6, lane = tid & 63;
  int lr = lane & 15, lg = lane >> 4;
  int rowbase = wave*16;
  bf16x8 a0 = *(const bf16x8*)&Ash[(rowbase+lr)*FPAD + lg*8];
  bf16x8 a1 = *(const bf16x8*)&Ash[(rowbase+lr)*FPAD + 32 + lg*8];
  float bf0 = bsh[rowbase + lg*4 + 0];
  float bg0 = bsh[rowbase + lg*4 + 1];
  float bf1 = bsh[rowbase + lg*4 + 2];
  float bg1 = bsh[rowbase + lg*4 + 3];
  int o0 = (rowbase >> 1) + lg*2;
  #pragma unroll
  for (int nt = 0; nt < 8; ++nt){
    bf16x8 b0 = *(const bf16x8*)&Bsh[(nt*16+lr)*FPAD + lg*8];
    bf16x8 b1 = *(const bf16x8*)&Bsh[(nt*16+lr)*FPAD + 32 + lg*8];
    f32x4 acc = {};
    acc = __builtin_amdgcn_mfma_f32_16x16x32_bf16(a0, b0, acc, 0,0,0);
    acc = __builtin_amdgcn_mfma_f32_16x16x32_bf16(a1, b1, acc, 0,0,0);
    int n = n0 + nt*16 + lr;
    if (n < NN){
      float f0 = acc[0] + bf0, g0 = acc[1] + bg0;
      float f1 = acc[2] + bf1, g1 = acc[3] + bg1;
      fg[((long)(b*32+o0)*Tp + t)*NN + n]   = f2b(ftanh_(f0)*fsig_(g0));
      fg[((long)(b*32+o0+1)*Tp + t)*NN + n] = f2b(ftanh_(f1)*fsig_(g1));
    }
  }
}

// ---------------- MFMA xg channel-mix: F = oma*(gcb + W0*F + W1*z1 + W2*z2) ----------------
__global__ __launch_bounds__(256) void k_xgmix_mfma(bfu* __restrict__ F,
    const bfu* __restrict__ z1, const bfu* __restrict__ z2,
    const float* __restrict__ Wl, const float* __restrict__ bl,
    const float* __restrict__ alpha, int Tp)
{
  __shared__ bfu Bsh[128*XPAD];
  __shared__ bfu Ash[32*XPAD];
  __shared__ float bsh[32];
  int tid = threadIdx.x;
  int tot6 = 6*Tp;
  int L = blockIdx.x + 6*(blockIdx.y + Tp*blockIdx.z);
  int xcd = L & 7, slot = L >> 3;
  int b = xcd + ((slot/tot6) << 3);
  int r6 = slot - (slot/tot6)*tot6;
  int t = r6/6, nb6 = r6 - (r6/6)*6;
  int n0 = nb6*128;
  // A = Wl rows directly: A[o][k], k-blocks = [W0 c][W1 c][W2 c]
  for (int i = tid; i < 3072; i += 256){
    int o = i/96, k = i - o*96;
    Ash[o*XPAD + k] = f2b(Wl[i]);
  }
  if (tid < 32) bsh[tid] = bl[tid];
  // B rows cc: 0..31 = F channels, 32..63 = z1, 64..95 = z2
  #pragma unroll
  for (int i = 0; i < 12; ++i){
    int idx = tid + i*256;
    int cc = idx % 96;
    int n4 = (idx / 96) * 4;
    const bfu* src = (cc < 32) ? F : ((cc < 64) ? z1 : z2);
    int c = cc & 31;
    long base = ((long)(b*32+c)*Tp + t)*NN + n0 + n4;
    ushort4 v = {0,0,0,0};
    if (n0 + n4 < NN) v = *(const ushort4*)(src + base);
    Bsh[(n4+0)*XPAD + cc] = v.x;
    Bsh[(n4+1)*XPAD + cc] = v.y;
    Bsh[(n4+2)*XPAD + cc] = v.z;
    Bsh[(n4+3)*XPAD + cc] = v.w;
  }
  __syncthreads();
  int wave = tid >> 6, lane = tid & 63;
  int lr = lane & 15, lg = lane >> 4;
  int rt = wave & 1;          // row tile (o 0-15 / 16-31)
  int ntb = wave >> 1;        // n-tile base (0/1), step 2
  bf16x8 a0 = *(const bf16x8*)&Ash[(rt*16+lr)*XPAD + 0  + lg*8];
  bf16x8 a1 = *(const bf16x8*)&Ash[(rt*16+lr)*XPAD + 32 + lg*8];
  bf16x8 a2 = *(const bf16x8*)&Ash[(rt*16+lr)*XPAD + 64 + lg*8];
  float oma = 1.f - sigmoidf_(alpha[0]);
  #pragma unroll
  for (int j = 0; j < 4; ++j){
    int nt = ntb + j*2;
    bf16x8 b0 = *(const bf16x8*)&Bsh[(nt*16+lr)*XPAD + 0  + lg*8];
    bf16x8 b1 = *(const bf16x8*)&Bsh[(nt*16+lr)*XPAD + 32 + lg*8];
    bf16x8 b2 = *(const bf16x8*)&Bsh[(nt*16+lr)*XPAD + 64 + lg*8];
    f32x4 acc = {};
    acc = __builtin_amdgcn_mfma_f32_16x16x32_bf16(a0, b0, acc, 0,0,0);
    acc = __builtin_amdgcn_mfma_f32_16x16x32_bf16(a1, b1, acc, 0,0,0);
    acc = __builtin_amdgcn_mfma_f32_16x16x32_bf16(a2, b2, acc, 0,0,0);
    int n = n0 + nt*16 + lr;
    if (n < NN){
      #pragma unroll
      for (int r = 0; r < 4; ++r){
        int o = rt*16 + lg*4 + r;
        F[((long)(b*32+o)*Tp + t)*NN + n] = f2b(oma*(acc[r] + bsh[o]));
      }
    }
  }
}

// ---------------- pivotal diffusion, fused both orders, compact outputs ----------------
// ApkR is [r][k] row-major -> float4 loads; xks/yks read as float4 broadcasts
__global__ __launch_bounds__(256) void k_pgdiff12(const bfu* __restrict__ X,
    float* __restrict__ U1, bfu* __restrict__ Y1k,
    float* __restrict__ U2, bfu* __restrict__ Y2k,
    const int* __restrict__ idxk, const float* __restrict__ uvec,
    const float* __restrict__ ApkR, const float* __restrict__ bnp,
    int M, int Trow, int Tcomp)
{
  __shared__ __align__(16) float xks[4][100];
  __shared__ __align__(16) float yks[4][100];
  int tid = threadIdx.x;
  int g = tid >> 6, lane = tid & 63;
  int m = blockIdx.x*4 + g;
  bool act = (m < M);
  float s = 0.f, sk = 0.f;
  if (act){
    int mrow = (m/Tcomp)*Trow + (m%Tcomp);
    const bfu* xr = X + (long)mrow*NN;
    #pragma unroll
    for (int q = 0; q < 12; ++q){
      int v = lane + q*64;
      if (v < NN) s += b2f(xr[v]);
    }
    for (int o = 32; o; o >>= 1) s += __shfl_xor(s, o, 64);
    #pragma unroll
    for (int q = 0; q < 2; ++q){
      int k = lane + q*64;
      if (k < 100){
        float v = b2f(xr[idxk[k]]);
        xks[g][k] = v;
        sk += v;
      }
    }
    for (int o = 32; o; o >>= 1) sk += __shfl_xor(sk, o, 64);
  }
  __syncthreads();
  float u1val = 0.f, sumY = 0.f;
  if (act){
    int c = (m / Tcomp) & 31;
    float sb = bnp[c*2], bb = bnp[c*2+1];
    u1val = sb*(s*(1.f/716.f)) + bb;
    if (lane == 0) U1[m] = u1val;
    #pragma unroll
    for (int q = 0; q < 2; ++q){
      int r = lane + q*64;
      if (r < 100){
        const float4* ap4 = (const float4*)(ApkR + r*100);
        const float4* xv4 = (const float4*)xks[g];
        float acc = uvec[r]*(s - sk);
        #pragma unroll 5
        for (int k4 = 0; k4 < 25; ++k4){
          float4 a = ap4[k4];
          float4 xv = xv4[k4];
          acc += a.x*xv.x;
          acc += a.y*xv.y;
          acc += a.z*xv.z;
          acc += a.w*xv.w;
        }
        bfu yv = f2b(sb*acc + bb);
        Y1k[(long)m*100 + r] = yv;
        float yf = b2f(yv);
        yks[g][r] = yf;
        sumY += yf;
      }
    }
    for (int o = 32; o; o >>= 1) sumY += __shfl_xor(sumY, o, 64);
  }
  __syncthreads();
  if (!act) return;
  float base = 616.f*u1val;
  if (lane == 0) U2[m] = (base + sumY)*(1.f/716.f);
  #pragma unroll
  for (int q = 0; q < 2; ++q){
    int r = lane + q*64;
    if (r < 100){
      const float4* ap4 = (const float4*)(ApkR + r*100);
      const float4* yv4 = (const float4*)yks[g];
      float acc = uvec[r]*base;
      #pragma unroll 5
      for (int k4 = 0; k4 < 25; ++k4){
        float4 a = ap4[k4];
        float4 yv = yv4[k4];
        acc += a.x*yv.x;
        acc += a.y*yv.y;
        acc += a.z*yv.z;
        acc += a.w*yv.w;
      }
      Y2k[(long)m*100 + r] = f2b(acc);
    }
  }
}

// premix
__global__ __launch_bounds__(256) void k_ymix(const float* __restrict__ U1,
    const float* __restrict__ U2, const bfu* __restrict__ Y1k, const bfu* __restrict__ Y2k,
    const float* __restrict__ pWl, float* __restrict__ V12, float* __restrict__ M12, int Tp)
{
  int t = blockIdx.x, b = blockIdx.y, tid = threadIdx.x;
  __shared__ float w1t[1024], w2t[1024];
  __shared__ float y1s[3200], y2s[3200];
  __shared__ float u1s[32], u2s[32];
  for (int i = tid; i < 1024; i += 256){
    int o = i & 31, c = i >> 5;
    w1t[c*32+o] = pWl[o*96+32+c];
    w2t[c*32+o] = pWl[o*96+64+c];
  }
  for (int i = tid; i < 3200; i += 256){
    int c = i/100, r = i - c*100;
    long m = (long)(b*32+c)*Tp + t;
    y1s[i] = b2f(Y1k[m*100 + r]);
    y2s[i] = b2f(Y2k[m*100 + r]);
  }
  if (tid < 32){
    long m = (long)(b*32+tid)*Tp + t;
    u1s[tid] = U1[m]; u2s[tid] = U2[m];
  }
  __syncthreads();
  for (int i = tid; i < 3200; i += 256){
    int r = i >> 5, o = i & 31;
    float acc = 0.f;
    #pragma unroll 8
    for (int c = 0; c < 32; ++c)
      acc += w1t[c*32+o]*y1s[c*100+r] + w2t[c*32+o]*y2s[c*100+r];
    M12[((long)(b*Tp+t)*100 + r)*32 + o] = acc;
  }
  if (tid < 32){
    float acc = 0.f;
    #pragma unroll 8
    for (int c = 0; c < 32; ++c)
      acc += w1t[c*32+tid]*u1s[c] + w2t[c*32+tid]*u2s[c];
    V12[(long)(b*Tp+t)*32 + tid] = acc;
  }
}

// ---------------- combine + skip + fused BN partials; 2 n/thread ----------------
__global__ __launch_bounds__(256) void k_combine3nc(const bfu* __restrict__ x,
    bfu* __restrict__ F, const int* __restrict__ rankv,
    const float* __restrict__ M12, const float* __restrict__ V12,
    const float* __restrict__ pWl, const float* __restrict__ pbl,
    const float* __restrict__ skWl, const float* __restrict__ skbl,
    const float* __restrict__ alpha, const float* __restrict__ bnp,
    bfu* __restrict__ skipP, float* __restrict__ bnred,
    int T, int Tp, int d, int off2)
{
  __shared__ float w0t[1024];
  __shared__ bfu Msb[101*34];      // bf16, stride 34 (bank spread on sel)
  __shared__ float swt[256], bnl[64], pbs[32], sb8[8];
  int tid = threadIdx.x;
  int tot2 = 2*Tp;
  int L = blockIdx.x + 2*(blockIdx.y + Tp*blockIdx.z);
  int xcd = L & 7, slot = L >> 3;
  int b = xcd + ((slot/tot2) << 3);
  int r2 = slot - (slot/tot2)*tot2;
  int t = r2/2, bx2 = r2 & 1;
  for (int i = tid; i < 1024; i += 256){
    int o = i & 31, c = i >> 5;
    w0t[c*32+o] = pWl[o*96+c];
  }
  for (int i = tid; i < 3434; i += 256){
    int r = i/34, o = i - r*34;
    if (o < 32)
      Msb[r*34+o] = f2b((r < 100) ? M12[((long)(b*Tp+t)*100 + r)*32 + o]
                                  : V12[(long)(b*Tp+t)*32 + o]);
  }
  swt[tid] = skWl[tid];
  if (tid < 64) bnl[tid] = bnp[tid];
  if (tid < 32) pbs[tid] = pbl[tid];
  if (tid < 8)  sb8[tid] = skbl[tid];
  __syncthreads();
  int n = bx2*512 + tid*2;
  bool act = (n < NN);
  float ax[32], ay[32];
  #pragma unroll
  for (int o = 0; o < 32; ++o){ ax[o] = pbs[o]; ay[o] = pbs[o]; }
  const float4* w04 = (const float4*)w0t;
  if (act){
    #pragma unroll 2
    for (int c = 0; c < 32; ++c){
      float sc = bnl[c*2], bc = bnl[c*2+1];
      ushort2 xv = *(const ushort2*)(x + ((long)(b*32+c)*T + t)*NN + n);
      float x0 = b2f(xv.x)*sc + bc;
      float x1 = b2f(xv.y)*sc + bc;
      #pragma unroll
      for (int o4 = 0; o4 < 8; ++o4){
        float4 w = w04[c*8+o4];
        ax[o4*4+0] += w.x*x0;  ay[o4*4+0] += w.x*x1;
        ax[o4*4+1] += w.y*x0;  ay[o4*4+1] += w.y*x1;
        ax[o4*4+2] += w.z*x0;  ay[o4*4+2] += w.z*x1;
        ax[o4*4+3] += w.w*x0;  ay[o4*4+3] += w.w*x1;
      }
    }
  }
  int ra = act ? rankv[n]   : -1;
  int rb = act ? rankv[n+1] : -1;
  int sela = (ra < 0) ? 100 : ra;
  int selb = (rb < 0) ? 100 : rb;
  float a_s = sigmoidf_(alpha[0]);
  #pragma unroll
  for (int o = 0; o < 32; ++o){
    float v0 = 0.f, v1 = 0.f;
    if (act){
      float scb = bnl[o*2], bcb = bnl[o*2+1];
      long oidx = ((long)(b*32+o)*Tp + t)*NN + n;
      ushort2 gv = *(const ushort2*)(F + oidx);
      ushort2 rv = *(const ushort2*)(x + ((long)(b*32+o)*T + t + d)*NN + n);
      v0 = a_s*(ax[o] + b2f(Msb[sela*34+o])) + b2f(gv.x) + b2f(rv.x)*scb + bcb;
      v1 = a_s*(ay[o] + b2f(Msb[selb*34+o])) + b2f(gv.y) + b2f(rv.y)*scb + bcb;
      ushort2 ov; ov.x = f2b(v0); ov.y = f2b(v1);
      *(ushort2*)(F + oidx) = ov;
    }
    ax[o] = v0; ay[o] = v1;
  }
  {
    int wave = tid >> 6;
    int gid = ((blockIdx.x + gridDim.x*(blockIdx.y + gridDim.y*blockIdx.z)) << 2) + wave;
    #pragma unroll
    for (int o = 0; o < 32; ++o){
      float v  = ax[o] + ay[o];
      float vq = ax[o]*ax[o] + ay[o]*ay[o];
      for (int s = 32; s; s >>= 1){
        v  += __shfl_xor(v,  s, 64);
        vq += __shfl_xor(vq, s, 64);
      }
      if ((tid & 63) == 0){
        bnred[((long)o*MAXG + gid)*2]     = v;
        bnred[((long)o*MAXG + gid)*2 + 1] = vq;
      }
    }
  }
  if (!act) return;
  const float4* sw4 = (const float4*)swt;
  #pragma unroll
  for (int sc2 = 0; sc2 < 8; ++sc2){
    float s0 = sb8[sc2], s1 = sb8[sc2];
    #pragma unroll
    for (int c4 = 0; c4 < 8; ++c4){
      float4 w = sw4[sc2*8 + c4];
      s0 += w.x*ax[c4*4] + w.y*ax[c4*4+1] + w.z*ax[c4*4+2] + w.w*ax[c4*4+3];
      s1 += w.x*ay[c4*4] + w.y*ay[c4*4+1] + w.z*ay[c4*4+2] + w.w*ay[c4*4+3];
    }
    ushort2 ov; ov.x = f2b(fmaxf(s0, 0.f)); ov.y = f2b(fmaxf(s1, 0.f));
    *(ushort2*)(skipP + ((long)b*416 + off2 + t*8 + sc2)*NN + n) = ov;
  }
}

// reduce per-wave BN partials -> bnp
__global__ void k_bn2v2(const float* __restrict__ red, const float* __restrict__ gamma,
                        const float* __restrict__ beta, float* __restrict__ bnp,
                        int layer, int Tp, int ngroups){
  int c = blockIdx.x, tid = threadIdx.x;
  float s = 0.f, s2 = 0.f;
  for (int g = tid; g < ngroups; g += 256){
    s  += red[((long)c*MAXG + g)*2];
    s2 += red[((long)c*MAXG + g)*2 + 1];
  }
  __shared__ float rs[256], rs2[256];
  rs[tid] = s; rs2[tid] = s2; __syncthreads();
  for (int k = 128; k > 0; k >>= 1){
    if (tid < k){ rs[tid] += rs[tid+k]; rs2[tid] += rs2[tid+k]; }
    __syncthreads();
  }
  if (tid == 0){
    float cnt = 64.f*Tp*716.f;
    float mu = rs[0]/cnt, var = rs2[0]/cnt - mu*mu;
    float rstd = rsqrtf(var + 1e-5f);
    float ga = gamma[layer*32+c], be = beta[layer*32+c];
    bnp[c*2] = rstd*ga; bnp[c*2+1] = be - mu*rstd*ga;
  }
}

// ---------------- end MLP ----------------

__global__ __launch_bounds__(256) void k_sktr(const bfu* __restrict__ SP, bfu* __restrict__ ST){
  __shared__ bfu tile[64][66];
  int b = blockIdx.z;
  int n0 = blockIdx.x*64, k0 = blockIdx.y*64;
  int tid = threadIdx.x;
  int tr = tid >> 6, tc = tid & 63;
  #pragma unroll
  for (int p = 0; p < 16; ++p){
    int k = k0 + p*4 + tr, n = n0 + tc;
    tile[p*4+tr][tc] = (k < 416 && n < NN) ? SP[((long)b*416 + k)*NN + n] : (bfu)0;
  }
  __syncthreads();
  #pragma unroll
  for (int p = 0; p < 16; ++p){
    int n = n0 + p*4 + tr, k = k0 + tc;
    if (n < NN && k < 416) ST[((long)b*NN + n)*416 + k] = tile[tc][p*4+tr];
  }
}

__global__ __launch_bounds__(256) void k_end2(const bfu* __restrict__ H,
    const float* __restrict__ W2, const float* __restrict__ b2, float* __restrict__ out)
{
  __shared__ float w[12*512];
  for (int i = threadIdx.x; i < 6144; i += 256) w[i] = W2[i];
  __syncthreads();
  int n = blockIdx.x*256 + threadIdx.x; if (n >= NN) return;
  int b = blockIdx.y;
  float acc[12];
  #pragma unroll
  for (int o = 0; o < 12; ++o) acc[o] = b2[o];
  for (int e = 0; e < 512; ++e){
    float h = b2f(H[((long)b*512+e)*NN + n]);
    #pragma unroll
    for (int o = 0; o < 12; ++o) acc[o] += w[o*512+e]*h;
  }
  #pragma unroll
  for (int o = 0; o < 12; ++o) out[((long)b*12+o)*NN + n] = acc[o];
}

// ---------------- launch ----------------

extern "C" void kernel_launch(void* const* d_in, const int* in_sizes, int n_in,
                              void* d_out, int out_size, void* d_ws, size_t ws_size,
                              hipStream_t stream)
{
  const float* hist = (const float*)d_in[0];
  const float* alpha = (const float*)d_in[1];
  const float* p1  = (const float*)d_in[2];
  const float* p2  = (const float*)d_in[3];
  const float* p3  = (const float*)d_in[4];
  const float* pk  = (const float*)d_in[5];
  const float* piv = (const float*)d_in[6];
  const float* sW  = (const float*)d_in[7];
  const float* sb  = (const float*)d_in[8];
  const float* saW = (const float*)d_in[9];
  const float* sab = (const float*)d_in[10];
  const float* fW  = (const float*)d_in[11];
  const float* fb  = (const float*)d_in[12];
  const float* gW  = (const float*)d_in[13];
  const float* gb  = (const float*)d_in[14];
  const float* skW = (const float*)d_in[15];
  const float* skb = (const float*)d_in[16];
  const float* gcW = (const float*)d_in[17];
  const float* gcb = (const float*)d_in[18];
  const float* pgW = (const float*)d_in[19];
  const float* pgb = (const float*)d_in[20];
  const float* bng = (const float*)d_in[21];
  const float* bnb = (const float*)d_in[22];
  const float* e1W = (const float*)d_in[23];
  const float* e1b = (const float*)d_in[24];
  const float* e2W = (const float*)d_in[25];
  const float* e2b = (const float*)d_in[26];
  float* out = (float*)d_out;

  char* base = (char*)d_ws;
  size_t off = 0;
  auto alloc = [&](size_t bytes)->char*{
    char* r = base + off;
    off = (off + bytes + 255) & ~(size_t)255;
    return r;
  };
  const size_t SZ12 = 64UL*32*12*716*2;
  const size_t SZ13 = 64UL*32*13*716*2;
  bfu*   t1    = (bfu*)  alloc(SZ12);
  bfu*   t2    = (bfu*)  alloc(SZ12);
  bfu*   P     = (bfu*)  alloc(SZ13);
  bfu*   Q     = (bfu*)  alloc(SZ12);
  bfu*   skipP = (bfu*)  alloc(64UL*416*716*2);
  bfu*   skipT = (bfu*)  alloc(64UL*716*416*2);
  float* adjp  = (float*)alloc((size_t)NSQ*4);
  float* tmp1  = (float*)alloc(64UL*1600*4);
  float* tmp2  = (float*)alloc(64UL*716*40*4);
  float* p3t   = (float*)alloc(40UL*716*4);
  bfu*   e1Wb  = (bfu*)  alloc(512UL*416*2);
  unsigned int* topA = (unsigned int*)alloc(64UL*NN*16*4);
  int*   cntA  = (int*)  alloc(64UL*NN*4);
  float* xs    = (float*)alloc(716UL*13*4);
  float* yv    = (float*)alloc(716UL*4);
  float* score = (float*)alloc(716UL*4);
  float* bnred = (float*)alloc(32UL*MAXG*2*4);
  float* bnp   = (float*)alloc(64UL*4);
  float* bnpid = (float*)alloc(64UL*4);
  float* uvec  = (float*)alloc(100UL*4);
  float* ApkR  = (float*)alloc(100UL*100*4);
  int*   ind   = (int*)  alloc(64UL*4);
  int*   mask  = (int*)  alloc(716UL*4);
  int*   idxk  = (int*)  alloc(100UL*4);
  int*   rankv = (int*)  alloc(716UL*4);

  // pgcn-compact buffers aliased INTO t1 (dead between k_xgmix_mfma and next gather)
  char* t1c = (char*)t1;
  float* U1  = (float*)(t1c);
  float* U2  = (float*)(t1c +   98304);
  float* V12 = (float*)(t1c + 2*98304);
  float* M12 = (float*)(t1c + 3*98304);
  bfu*   Y1k = (bfu*)  (t1c + 3*98304 + 9830400);
  bfu*   Y2k = (bfu*)  (t1c + 3*98304 + 9830400 + 4915200);

  bfu* hidden = t1;

  // dynamic adjacency (sparse capture)
  k_ind<<<1,64,0,stream>>>(hist, ind);
  k_dg1<<<64,256,0,stream>>>(p1, pk, ind, tmp1);
  k_dg2<<<dim3(112,64),256,0,stream>>>(p2, tmp1, tmp2);
  k_p3t<<<3,256,0,stream>>>(p3, p3t);
  k_adjrow4s<<<dim3(179,64),256,0,stream>>>(p3t, tmp2, topA, cntA);
  // pivotal adjacency (compact structure)
  k_xs<<<716,64,0,stream>>>(hist, saW, sab, xs, yv);
  k_adjp<<<dim3(3,716),256,0,stream>>>(xs, yv, piv, adjp);
  k_score<<<716,256,0,stream>>>(adjp, score);
  k_topk<<<1,256,0,stream>>>(score, mask);
  k_pivprep<<<1,256,0,stream>>>(adjp, mask, idxk, rankv, uvec, ApkR);
  // start conv + weight conversion + identity BN
  k_init_x<<<dim3(3,13,64),256,0,stream>>>(hist, sW, sb, P);
  k_e1perm<<<(512*416+255)/256,256,0,stream>>>(e1W, e1Wb);
  k_bnid<<<1,64,0,stream>>>(bnpid);

  int T = 13;
  bfu* x = P;
  bfu* F = Q;
  static const int off2_[8] = {0,96,176,248,304,352,384,408};
  for (int i = 0; i < 8; ++i){
    int d = (i & 1) ? 2 : 1;
    int Tp = T - d;
    const float* bnin = (i == 0) ? bnpid : bnp;
    dim3 g2n(2, Tp, 64);
    dim3 g6(6, Tp, 64);
    // MFMA gated conv, BN folded in-block
    k_fg_mfma<<<g6,256,0,stream>>>(x, fW + i*2048, fb + i*32, gW + i*2048, gb + i*32,
        bnin, F, T, Tp, d);
    // xg path: fused double sparse diffusion then MFMA channel-mix over F
    int M1 = 32*Tp; long sx1 = (long)M1*NN;
    dim3 gz((M1+3)/4, 64);
    k_zgather2<<<gz,256,0,stream>>>(F, topA, cntA, t1, t2, M1, sx1);
    k_xgmix_mfma<<<g6,256,0,stream>>>(F, t1, t2, gcW + i*3072, gcb + i*32, alpha, Tp);
    // pgcn path, compact (fused 1st+2nd diffusion; buffers live in dead t1)
    int M2 = 64*32*Tp;
    k_pgdiff12<<<M2/4,256,0,stream>>>(x, U1, Y1k, U2, Y2k, idxk, uvec, ApkR, bnin,
        M2, T, Tp);
    k_ymix<<<dim3(Tp,64),256,0,stream>>>(U1, U2, Y1k, Y2k, pgW + i*3072, V12, M12, Tp);
    // combine + residual + skip + fused BN partials (2 n/thread)
    k_combine3nc<<<g2n,256,0,stream>>>(x, F, rankv, M12, V12, pgW + i*3072, pgb + i*32,
        skW + i*256, skb + i*8, alpha, bnin, skipP, bnred, T, Tp, d, off2_[i]);
    int ngroups = 2*Tp*64*4;
    k_bn2v2<<<32,256,0,stream>>>(bnred, bng, bnb, bnp, i, Tp, ngroups);
    bfu* tmp = x; x = F; F = tmp;
    T = Tp;
  }
  // end MLP
  k_sktr<<<dim3(12,7,64),256,0,stream>>>(skipP, skipT);
  gemm_mfma<<<dim3(6,4,64),256,0,stream>>>(e1Wb, skipT, hidden, 512, 416,
      0L, 416L*716, 512L*716, e1b, 1, 1, 1);
  k_end2<<<dim3(3,64),256,0,stream>>>(hidden, e2W, e2b, out);
}

// Round 22
// 2789.623 us; speedup vs baseline: 1.0341x; 1.0341x over previous
//
#include <hip/hip_runtime.h>
#include <math.h>

#define NN 716
#define NSQ (716*716)
#define MAXG 9216
#define FPAD 70
#define XPAD 102
typedef unsigned short bfu;
typedef __attribute__((ext_vector_type(8))) __bf16 bf16x8;
typedef __attribute__((ext_vector_type(4))) float f32x4;

__device__ __forceinline__ float b2f(bfu u){ union{unsigned int i; float f;} x; x.i = ((unsigned int)u)<<16; return x.f; }
__device__ __forceinline__ bfu f2b(float f){ union{float fv; unsigned int i;} x; x.fv = f; unsigned int r = (x.i + 0x7fffu + ((x.i>>16)&1u)) >> 16; return (bfu)r; }
__device__ __forceinline__ float sigmoidf_(float x){ return 1.f/(1.f+expf(-x)); }

__device__ __forceinline__ float fexp_(float x){
#if __has_builtin(__builtin_amdgcn_exp2f)
  return __builtin_amdgcn_exp2f(x * 1.44269504088896340736f);
#else
  return __expf(x);
#endif
}
__device__ __forceinline__ float frcp_(float x){
#if __has_builtin(__builtin_amdgcn_rcpf)
  return __builtin_amdgcn_rcpf(x);
#else
  return 1.f/x;
#endif
}
__device__ __forceinline__ float fsig_(float x){ return frcp_(1.f + fexp_(-x)); }
__device__ __forceinline__ float ftanh_(float x){
  float xc = fminf(fmaxf(x, -30.f), 30.f);
  float e = fexp_(-2.f*xc);
  return (1.f - e) * frcp_(1.f + e);
}

// ---------------- init / adjacency construction ----------------

__global__ void k_ind(const float* __restrict__ hist, int* __restrict__ ind){
  int b = threadIdx.x; if (b >= 64) return;
  float v = hist[((b*12+11)*NN + 0)*2 + 1];
  ind[b] = ((int)(v*288.0f)) % 288;
}

__global__ void k_dg1(const float* __restrict__ p1, const float* __restrict__ pk,
                      const int* __restrict__ ind, float* __restrict__ tmp1){
  int b = blockIdx.x;
  __shared__ float p1s[40];
  if (threadIdx.x < 40) p1s[threadIdx.x] = p1[ind[b]*40 + threadIdx.x];
  __syncthreads();
  for (int jk = threadIdx.x; jk < 1600; jk += 256){
    float acc = 0.f;
    for (int i = 0; i < 40; ++i) acc += p1s[i]*pk[i*1600 + jk];
    tmp1[b*1600 + jk] = acc;
  }
}

__global__ void k_dg2(const float* __restrict__ p2, const float* __restrict__ tmp1,
                      float* __restrict__ tmp2){
  int b = blockIdx.y;
  __shared__ float ts[1600];
  for (int i = threadIdx.x; i < 1600; i += 256) ts[i] = tmp1[b*1600+i];
  __syncthreads();
  int idx = blockIdx.x*256 + threadIdx.x;
  if (idx >= NN*40) return;
  int n = idx/40, k = idx%40;
  float acc = 0.f;
  for (int j = 0; j < 40; ++j) acc += p2[n*40+j]*ts[j*40+k];
  tmp2[(long)b*NN*40 + idx] = acc;
}

__global__ void k_p3t(const float* __restrict__ p3, float* __restrict__ p3t){
  int v = blockIdx.x*256 + threadIdx.x; if (v >= NN) return;
  for (int k = 0; k < 40; ++k) p3t[k*NN + v] = p3[v*40 + k];
}

// 4 adjacency rows per block: logits -> relu -> softmax -> SPARSE top-16 capture
__global__ __launch_bounds__(256) void k_adjrow4s(const float* __restrict__ p3t,
    const float* __restrict__ tmp2, unsigned int* __restrict__ topA,
    int* __restrict__ cntA)
{
  int b = blockIdx.y, w0 = blockIdx.x*4, tid = threadIdx.x;
  int wave = tid >> 6, lane = tid & 63;
  __shared__ float t2s[4][40];
  __shared__ float buf[4][720];
  __shared__ float wred[4][4];
  __shared__ float rstat[4];
  __shared__ int pc[4][12];
  for (int i = tid; i < 160; i += 256){
    int r = i/40, k = i%40; int w = w0 + r;
    t2s[r][k] = (w < NN) ? tmp2[((long)b*NN + w)*40 + k] : 0.f;
  }
  __syncthreads();
  float lmax[4] = {0,0,0,0};
  for (int q = 0; q < 3; ++q){
    int v = tid + q*256;
    if (v < NN){
      float a[4] = {0,0,0,0};
      #pragma unroll 8
      for (int k = 0; k < 40; ++k){
        float pv = p3t[k*NN + v];
        #pragma unroll
        for (int r = 0; r < 4; ++r) a[r] += t2s[r][k]*pv;
      }
      #pragma unroll
      for (int r = 0; r < 4; ++r){
        float val = fmaxf(a[r], 0.f);
        buf[r][v] = val;
        lmax[r] = fmaxf(lmax[r], val);
      }
    }
  }
  #pragma unroll
  for (int r = 0; r < 4; ++r){
    float m = lmax[r];
    for (int s = 32; s > 0; s >>= 1) m = fmaxf(m, __shfl_xor(m, s, 64));
    if (lane == 0) wred[r][wave] = m;
  }
  __syncthreads();
  if (tid < 4) rstat[tid] = fmaxf(fmaxf(wred[tid][0], wred[tid][1]), fmaxf(wred[tid][2], wred[tid][3]));
  __syncthreads();
  float lsum[4] = {0,0,0,0};
  for (int q = 0; q < 3; ++q){
    int v = tid + q*256;
    if (v < NN){
      #pragma unroll
      for (int r = 0; r < 4; ++r){
        float e = fexp_(buf[r][v] - rstat[r]);
        buf[r][v] = e;
        lsum[r] += e;
      }
    }
  }
  __syncthreads();
  #pragma unroll
  for (int r = 0; r < 4; ++r){
    float s = lsum[r];
    for (int k = 32; k > 0; k >>= 1) s += __shfl_xor(s, k, 64);
    if (lane == 0) wred[r][wave] = s;
  }
  __syncthreads();
  if (tid < 4) rstat[tid] = frcp_(wred[tid][0] + wred[tid][1] + wred[tid][2] + wred[tid][3]);
  __syncthreads();
  for (int q = 0; q < 3; ++q){
    int v = tid + q*256;
    #pragma unroll
    for (int r = 0; r < 4; ++r){
      float p = (v < NN) ? buf[r][v]*rstat[r] : 0.f;
      unsigned long long m = __ballot(p >= 1e-7f);
      if (lane == 0) pc[r][q*4+wave] = __popcll(m);
    }
  }
  __syncthreads();
  for (int q = 0; q < 3; ++q){
    int v = tid + q*256;
    #pragma unroll
    for (int r = 0; r < 4; ++r){
      float p = (v < NN) ? buf[r][v]*rstat[r] : 0.f;
      bool qual = (p >= 1e-7f);
      unsigned long long m = __ballot(qual);
      int w = w0 + r;
      if (qual && w < NN){
        int base = 0, me = q*4+wave;
        for (int s = 0; s < me; ++s) base += pc[r][s];
        unsigned long long below = (lane == 0) ? 0ull : (m << (64-lane) >> (64-lane));
        int pos = base + __popcll(below);
        if (pos < 16)
          topA[((long)b*NN + w)*16 + pos] = (((unsigned)v)<<16) | (unsigned)f2b(p);
      }
    }
  }
  __syncthreads();
  if (tid < 4){
    int w = w0 + tid;
    if (w < NN){
      int tot = 0;
      for (int s = 0; s < 12; ++s) tot += pc[tid][s];
      cntA[(long)b*NN + w] = (tot < 16) ? tot : 16;
    }
  }
}

// fused double sparse diffusion: z1[m] = A-gather(X[m]); z2[m] = A-gather(z1[m])
__global__ __launch_bounds__(256) void k_zgather2(const bfu* __restrict__ Xg,
    const unsigned int* __restrict__ topA, const int* __restrict__ cntA,
    bfu* __restrict__ Z1g, bfu* __restrict__ Z2g, int M, long sx)
{
  __shared__ bfu rows[4][720];
  __shared__ bfu zrow[4][720];
  int b = blockIdx.y;
  int tid = threadIdx.x, wave = tid >> 6, lane = tid & 63;
  int m = blockIdx.x*4 + wave;
  if (m < M){
    const bfu* xr = Xg + (long)b*sx + (long)m*NN;
    #pragma unroll
    for (int q = 0; q < 12; ++q){
      int v = lane + q*64;
      if (v < NN) rows[wave][v] = xr[v];
    }
  }
  __syncthreads();
  const unsigned int* ta = topA + (long)b*NN*16;
  const int* ca = cntA + (long)b*NN;
  if (m < M){
    bfu* zr = Z1g + (long)b*sx + (long)m*NN;
    #pragma unroll
    for (int q = 0; q < 12; ++q){
      int w = lane + q*64;
      if (w < NN){
        int cnt = ca[w];
        const unsigned int* lst = ta + (long)w*16;
        float acc = 0.f;
        for (int j = 0; j < cnt; ++j){
          unsigned int e = lst[j];
          acc += b2f((bfu)(e & 0xffffu)) * b2f(rows[wave][e >> 16]);
        }
        bfu zv = f2b(acc);
        zr[w] = zv;
        zrow[wave][w] = zv;
      }
    }
  }
  __syncthreads();
  if (m >= M) return;
  bfu* z2r = Z2g + (long)b*sx + (long)m*NN;
  #pragma unroll
  for (int q = 0; q < 12; ++q){
    int w = lane + q*64;
    if (w < NN){
      int cnt = ca[w];
      const unsigned int* lst = ta + (long)w*16;
      float acc = 0.f;
      for (int j = 0; j < cnt; ++j){
        unsigned int e = lst[j];
        acc += b2f((bfu)(e & 0xffffu)) * b2f(zrow[wave][e >> 16]);
      }
      z2r[w] = f2b(acc);
    }
  }
}

// xs[n][t] = sum_b x_a[b,n,t]; y[n] = sum_t xs[n][t]
__global__ void k_xs(const float* __restrict__ hist, const float* __restrict__ saW,
                     const float* __restrict__ sab, float* __restrict__ xs, float* __restrict__ y){
  int n = blockIdx.x, b = threadIdx.x; // 64 threads
  float w = saW[0], bb = sab[0];
  float ytot = 0.f;
  for (int t = 0; t < 13; ++t){
    float inp = (t == 0) ? 0.f : hist[((b*12 + (t-1))*NN + n)*2];
    float s = inp;
    for (int off = 32; off > 0; off >>= 1) s += __shfl_down(s, off, 64);
    if (b == 0){ float val = w*s + 64.f*bb; xs[n*13+t] = val; ytot += val; }
  }
  if (b == 0) y[n] = ytot;
}

__global__ void k_adjp(const float* __restrict__ xs, const float* __restrict__ y,
                       const float* __restrict__ piv, float* __restrict__ adjp){
  int i = blockIdx.y;
  __shared__ float xi[13];
  if (threadIdx.x < 13) xi[threadIdx.x] = xs[i*13+threadIdx.x];
  __syncthreads();
  int j = blockIdx.x*256 + threadIdx.x;
  if (j >= NN) return;
  float acc = 0.f;
  #pragma unroll
  for (int t = 0; t < 12; ++t) acc += xi[t]*xs[j*13+t+1];
  adjp[(long)i*NN+j] = acc / y[j] * piv[(long)i*NN+j];
}

__global__ void k_score(const float* __restrict__ adjp, float* __restrict__ score){
  int n = blockIdx.x, tid = threadIdx.x;
  float s = 0.f;
  for (int i = tid; i < NN; i += 256) s += adjp[(long)i*NN+n] + adjp[(long)n*NN+i];
  __shared__ float red[256];
  red[tid] = s; __syncthreads();
  for (int k = 128; k > 0; k >>= 1){ if (tid < k) red[tid] += red[tid+k]; __syncthreads(); }
  if (tid == 0) score[n] = red[0];
}

// bitonic sort 1024 (desc, tie->lower index first), take top 100 -> mask
__global__ void k_topk(const float* __restrict__ score, int* __restrict__ mask){
  __shared__ float v[1024];
  __shared__ int ix[1024];
  int tid = threadIdx.x;
  for (int t = tid; t < 1024; t += 256){ v[t] = (t < NN) ? score[t] : -INFINITY; ix[t] = t; }
  __syncthreads();
  for (int k = 2; k <= 1024; k <<= 1){
    for (int j = k >> 1; j > 0; j >>= 1){
      for (int t = tid; t < 1024; t += 256){
        int l = t ^ j;
        if (l > t){
          bool up = ((t & k) == 0);
          bool g = (v[t] > v[l]) || (v[t] == v[l] && ix[t] < ix[l]);
          if (up ? !g : g){
            float tv = v[t]; v[t] = v[l]; v[l] = tv;
            int ti = ix[t]; ix[t] = ix[l]; ix[l] = ti;
          }
        }
      }
      __syncthreads();
    }
  }
  for (int t = tid; t < NN; t += 256) mask[t] = 0;
  __syncthreads();
  if (tid < 100) mask[ix[tid]] = 1;
}

// build compact pivotal structure: idx[100], rank[716], u[100], ApkT[100k][100r]
__global__ void k_pivprep(const float* __restrict__ adjp, const int* __restrict__ mask,
                          int* __restrict__ idxk, int* __restrict__ rankv,
                          float* __restrict__ uvec, float* __restrict__ ApkT){
  __shared__ int sidx[100];
  int tid = threadIdx.x;
  if (tid == 0){
    int c = 0;
    for (int i = 0; i < NN; ++i){
      if (mask[i] && c < 100){ sidx[c] = i; idxk[c] = i; rankv[i] = c; ++c; }
      else rankv[i] = -1;
    }
  }
  __syncthreads();
  if (tid < 100){
    int i = sidx[tid];
    const float* row = adjp + (long)i*NN;
    float mx = 0.f;
    for (int k = 0; k < 100; ++k) mx = fmaxf(mx, row[sidx[k]]);
    float sum = 616.f * fexp_(-mx);
    for (int k = 0; k < 100; ++k) sum += fexp_(fmaxf(row[sidx[k]], 0.f) - mx);
    float inv = 1.f/sum;
    uvec[tid] = fexp_(-mx)*inv;
    for (int k = 0; k < 100; ++k)
      ApkT[k*100 + tid] = fexp_(fmaxf(row[sidx[k]], 0.f) - mx)*inv;
  }
}

// x[b,c,t,n] = start_W[c]*inp + start_b[c]
__global__ void k_init_x(const float* __restrict__ hist, const float* __restrict__ sW,
                         const float* __restrict__ sb, bfu* __restrict__ x){
  int n = blockIdx.x*256 + threadIdx.x; if (n >= NN) return;
  int t = blockIdx.y, b = blockIdx.z;
  float inp = (t == 0) ? 0.f : hist[((b*12 + (t-1))*NN + n)*2];
  #pragma unroll
  for (int c = 0; c < 32; ++c)
    x[((long)(b*32+c)*13 + t)*NN + n] = f2b(sW[c]*inp + sb[c]);
}

// identity BN params
__global__ void k_bnid(float* __restrict__ bnp){
  int c = threadIdx.x; if (c >= 32) return;
  bnp[c*2] = 1.f; bnp[c*2+1] = 0.f;
}

// permuted e1W -> bf16
__global__ void k_e1perm(const float* __restrict__ W, bfu* __restrict__ Wb){
  int i = blockIdx.x*256 + threadIdx.x;
  if (i >= 512*416) return;
  int e = i/416, kp = i%416;
  const int off2[9] = {0,96,176,248,304,352,384,408,416};
  const int soff[8] = {320,240,168,112,64,32,8,0};
  const int tpl[8]  = {12,10,9,7,6,4,3,1};
  int L = 0;
  #pragma unroll
  for (int q = 0; q < 8; ++q) if (kp >= off2[q+1]) L = q+1;
  int r = kp - off2[L]; int t = r>>3, sc = r&7;
  int k = soff[L] + sc*tpl[L] + t;
  Wb[e*416+kp] = f2b(W[e*416+k]);
}

// ---------------- MFMA GEMM (end1 only) ----------------
#define LDST 44

__global__ __launch_bounds__(256) void gemm_mfma(const bfu* __restrict__ Xg,
    const bfu* __restrict__ Ag, bfu* __restrict__ Cg,
    int M, int K, long sx, long sa, long sc,
    const float* __restrict__ bias, int relu_out, int Trow, int Tcomp)
{
  int bx = gridDim.x, by = gridDim.y, nb = gridDim.z;
  int bX = blockIdx.x, bY = blockIdx.y, bZ = blockIdx.z;
  int bpb = bx*by, total = bpb*nb;
  if ((total & 7) == 0 && (nb & 7) == 0){
    int L = bX + bx*(bY + by*bZ);
    int xcd = L & 7, slot = L >> 3;
    bZ = xcd*(nb >> 3) + slot/bpb;
    int inner = slot % bpb;
    bX = inner % bx; bY = inner / bx;
  }
  const bfu* X = Xg + (long)bZ*sx;
  const bfu* A = Ag + (long)bZ*sa;
  bfu*       C = Cg + (long)bZ*sc;
  int m0 = bY*128, n0 = bX*128;
  __shared__ bfu Xs[128*LDST];
  __shared__ bfu As[128*LDST];
  int tid = threadIdx.x;
  int wave = tid >> 6, lane = tid & 63;
  int wm = (wave >> 1)*64, wn = (wave & 1)*64;
  int lr = lane & 15, lg = lane >> 4;
  f32x4 acc[4][4] = {};
  int ldr = tid >> 1, ldk = (tid & 1)*16;
  int mg = m0 + ldr, ng = n0 + ldr;
  int mrow = (Trow == Tcomp) ? mg : (mg/Tcomp)*Trow + (mg%Tcomp);
  const bfu* xrow = X + (long)mrow*K;
  const bfu* arow = A + (long)ng*K;
  for (int k0 = 0; k0 < K; k0 += 32){
    int kk = k0 + ldk;
    ushort4 z4 = {0,0,0,0};
    ushort4 x0=z4,x1=z4,x2=z4,x3=z4, a0=z4,a1=z4,a2=z4,a3=z4;
    if (mg < M){
      if (kk + 16 <= K){
        const ushort4* s = (const ushort4*)(xrow + kk);
        x0=s[0]; x1=s[1]; x2=s[2]; x3=s[3];
      } else {
        bfu tv[16];
        #pragma unroll
        for (int j=0;j<16;++j) tv[j] = (kk+j < K) ? xrow[kk+j] : (bfu)0;
        const ushort4* s = (const ushort4*)tv;
        x0=s[0]; x1=s[1]; x2=s[2]; x3=s[3];
      }
    }
    if (ng < NN){
      if (kk + 16 <= K){
        const ushort4* s = (const ushort4*)(arow + kk);
        a0=s[0]; a1=s[1]; a2=s[2]; a3=s[3];
      } else {
        bfu tv[16];
        #pragma unroll
        for (int j=0;j<16;++j) tv[j] = (kk+j < K) ? arow[kk+j] : (bfu)0;
        const ushort4* s = (const ushort4*)tv;
        a0=s[0]; a1=s[1]; a2=s[2]; a3=s[3];
      }
    }
    ushort4* xd = (ushort4*)&Xs[ldr*LDST + ldk];
    xd[0]=x0; xd[1]=x1; xd[2]=x2; xd[3]=x3;
    ushort4* ad = (ushort4*)&As[ldr*LDST + ldk];
    ad[0]=a0; ad[1]=a1; ad[2]=a2; ad[3]=a3;
    __syncthreads();
    bf16x8 af[4], bfr[4];
    #pragma unroll
    for (int i=0;i<4;++i){
      af[i]  = *(const bf16x8*)&Xs[(wm + i*16 + lr)*LDST + lg*8];
      bfr[i] = *(const bf16x8*)&As[(wn + i*16 + lr)*LDST + lg*8];
    }
    #pragma unroll
    for (int i=0;i<4;++i)
      #pragma unroll
      for (int j=0;j<4;++j)
        acc[i][j] = __builtin_amdgcn_mfma_f32_16x16x32_bf16(af[i], bfr[j], acc[i][j], 0,0,0);
    __syncthreads();
  }
  #pragma unroll
  for (int i=0;i<4;++i){
    #pragma unroll
    for (int r=0;r<4;++r){
      int m = m0 + wm + i*16 + lg*4 + r;
      if (m >= M) continue;
      float bv = bias ? bias[m] : 0.f;
      #pragma unroll
      for (int j=0;j<4;++j){
        int n = n0 + wn + j*16 + lr;
        if (n < NN){
          float v = acc[i][j][r] + bv;
          if (relu_out) v = fmaxf(v, 0.f);
          C[(long)m*NN + n] = f2b(v);
        }
      }
    }
  }
}

// ---------------- MFMA gated temporal conv (128 n / block, XCD-grouped, BN-folded in-block) ----------------
__global__ __launch_bounds__(256) void k_fg_mfma(const bfu* __restrict__ x,
    const float* __restrict__ fWl, const float* __restrict__ fbl,
    const float* __restrict__ gWl, const float* __restrict__ gbl,
    const float* __restrict__ bnp, bfu* __restrict__ fg, int T, int Tp, int d)
{
  __shared__ bfu Bsh[128*FPAD];
  __shared__ bfu Ash[64*FPAD];
  __shared__ float bsh[64];
  int tid = threadIdx.x;
  int tot6 = 6*Tp;
  int L = blockIdx.x + 6*(blockIdx.y + Tp*blockIdx.z);
  int xcd = L & 7, slot = L >> 3;
  int b = xcd + ((slot/tot6) << 3);
  int r6 = slot - (slot/tot6)*tot6;
  int t = r6/6, nb6 = r6 - (r6/6)*6;
  int n0 = nb6*128;
  // weight staging with BN fold computed in-block
  for (int i = tid; i < 4096; i += 256){
    int row = i >> 6, k = i & 63;
    int o = row >> 1, isg = row & 1;
    int tap = k >> 5, c = k & 31;
    const float* W = isg ? gWl : fWl;
    Ash[row*FPAD + k] = f2b(W[(o*32+c)*2 + tap] * bnp[c*2]);
  }
  if (tid < 64){
    int o = tid >> 1, isg = tid & 1;
    const float* W = isg ? gWl : fWl;
    const float* B = isg ? gbl : fbl;
    float s = B[o];
    for (int c = 0; c < 32; ++c)
      s += (W[(o*32+c)*2] + W[(o*32+c)*2+1]) * bnp[c*2+1];
    bsh[tid] = s;
  }
  #pragma unroll
  for (int i = 0; i < 8; ++i){
    int idx = tid + i*256;
    int n4 = (idx & 31)*4;
    int cc = idx >> 5;
    int c = cc & 31, tap = cc >> 5;
    long base = ((long)(b*32+c)*T + t + (tap ? d : 0))*NN + n0 + n4;
    ushort4 v = {0,0,0,0};
    if (n0 + n4 < NN) v = *(const ushort4*)(x + base);
    Bsh[(n4+0)*FPAD + cc] = v.x;
    Bsh[(n4+1)*FPAD + cc] = v.y;
    Bsh[(n4+2)*FPAD + cc] = v.z;
    Bsh[(n4+3)*FPAD + cc] = v.w;
  }
  __syncthreads();
  int wave = tid >> 6, lane = tid & 63;
  int lr = lane & 15, lg = lane >> 4;
  int rowbase = wave*16;
  bf16x8 a0 = *(const bf16x8*)&Ash[(rowbase+lr)*FPAD + lg*8];
  bf16x8 a1 = *(const bf16x8*)&Ash[(rowbase+lr)*FPAD + 32 + lg*8];
  float bf0 = bsh[rowbase + lg*4 + 0];
  float bg0 = bsh[rowbase + lg*4 + 1];
  float bf1 = bsh[rowbase + lg*4 + 2];
  float bg1 = bsh[rowbase + lg*4 + 3];
  int o0 = (rowbase >> 1) + lg*2;
  #pragma unroll
  for (int nt = 0; nt < 8; ++nt){
    bf16x8 b0 = *(const bf16x8*)&Bsh[(nt*16+lr)*FPAD + lg*8];
    bf16x8 b1 = *(const bf16x8*)&Bsh[(nt*16+lr)*FPAD + 32 + lg*8];
    f32x4 acc = {};
    acc = __builtin_amdgcn_mfma_f32_16x16x32_bf16(a0, b0, acc, 0,0,0);
    acc = __builtin_amdgcn_mfma_f32_16x16x32_bf16(a1, b1, acc, 0,0,0);
    int n = n0 + nt*16 + lr;
    if (n < NN){
      float f0 = acc[0] + bf0, g0 = acc[1] + bg0;
      float f1 = acc[2] + bf1, g1 = acc[3] + bg1;
      fg[((long)(b*32+o0)*Tp + t)*NN + n]   = f2b(ftanh_(f0)*fsig_(g0));
      fg[((long)(b*32+o0+1)*Tp + t)*NN + n] = f2b(ftanh_(f1)*fsig_(g1));
    }
  }
}

// ---------------- MFMA xg channel-mix: F = oma*(gcb + W0*F + W1*z1 + W2*z2) ----------------
__global__ __launch_bounds__(256) void k_xgmix_mfma(bfu* __restrict__ F,
    const bfu* __restrict__ z1, const bfu* __restrict__ z2,
    const float* __restrict__ Wl, const float* __restrict__ bl,
    const float* __restrict__ alpha, int Tp)
{
  __shared__ bfu Bsh[128*XPAD];
  __shared__ bfu Ash[32*XPAD];
  __shared__ float bsh[32];
  int tid = threadIdx.x;
  int tot6 = 6*Tp;
  int L = blockIdx.x + 6*(blockIdx.y + Tp*blockIdx.z);
  int xcd = L & 7, slot = L >> 3;
  int b = xcd + ((slot/tot6) << 3);
  int r6 = slot - (slot/tot6)*tot6;
  int t = r6/6, nb6 = r6 - (r6/6)*6;
  int n0 = nb6*128;
  // A = Wl rows directly: A[o][k], k-blocks = [W0 c][W1 c][W2 c]
  for (int i = tid; i < 3072; i += 256){
    int o = i/96, k = i - o*96;
    Ash[o*XPAD + k] = f2b(Wl[i]);
  }
  if (tid < 32) bsh[tid] = bl[tid];
  // B rows cc: 0..31 = F channels, 32..63 = z1, 64..95 = z2
  #pragma unroll
  for (int i = 0; i < 12; ++i){
    int idx = tid + i*256;
    int cc = idx % 96;
    int n4 = (idx / 96) * 4;
    const bfu* src = (cc < 32) ? F : ((cc < 64) ? z1 : z2);
    int c = cc & 31;
    long base = ((long)(b*32+c)*Tp + t)*NN + n0 + n4;
    ushort4 v = {0,0,0,0};
    if (n0 + n4 < NN) v = *(const ushort4*)(src + base);
    Bsh[(n4+0)*XPAD + cc] = v.x;
    Bsh[(n4+1)*XPAD + cc] = v.y;
    Bsh[(n4+2)*XPAD + cc] = v.z;
    Bsh[(n4+3)*XPAD + cc] = v.w;
  }
  __syncthreads();
  int wave = tid >> 6, lane = tid & 63;
  int lr = lane & 15, lg = lane >> 4;
  int rt = wave & 1;          // row tile (o 0-15 / 16-31)
  int ntb = wave >> 1;        // n-tile base (0/1), step 2
  bf16x8 a0 = *(const bf16x8*)&Ash[(rt*16+lr)*XPAD + 0  + lg*8];
  bf16x8 a1 = *(const bf16x8*)&Ash[(rt*16+lr)*XPAD + 32 + lg*8];
  bf16x8 a2 = *(const bf16x8*)&Ash[(rt*16+lr)*XPAD + 64 + lg*8];
  float oma = 1.f - sigmoidf_(alpha[0]);
  #pragma unroll
  for (int j = 0; j < 4; ++j){
    int nt = ntb + j*2;
    bf16x8 b0 = *(const bf16x8*)&Bsh[(nt*16+lr)*XPAD + 0  + lg*8];
    bf16x8 b1 = *(const bf16x8*)&Bsh[(nt*16+lr)*XPAD + 32 + lg*8];
    bf16x8 b2 = *(const bf16x8*)&Bsh[(nt*16+lr)*XPAD + 64 + lg*8];
    f32x4 acc = {};
    acc = __builtin_amdgcn_mfma_f32_16x16x32_bf16(a0, b0, acc, 0,0,0);
    acc = __builtin_amdgcn_mfma_f32_16x16x32_bf16(a1, b1, acc, 0,0,0);
    acc = __builtin_amdgcn_mfma_f32_16x16x32_bf16(a2, b2, acc, 0,0,0);
    int n = n0 + nt*16 + lr;
    if (n < NN){
      #pragma unroll
      for (int r = 0; r < 4; ++r){
        int o = rt*16 + lg*4 + r;
        F[((long)(b*32+o)*Tp + t)*NN + n] = f2b(oma*(acc[r] + bsh[o]));
      }
    }
  }
}

// ---------------- pivotal diffusion, fused both orders, compact outputs ----------------
// ApkT kept [k][r] (coalesced); lane l covers r=2l,2l+1 via float2 -> one pass
__global__ __launch_bounds__(256) void k_pgdiff12(const bfu* __restrict__ X,
    float* __restrict__ U1, bfu* __restrict__ Y1k,
    float* __restrict__ U2, bfu* __restrict__ Y2k,
    const int* __restrict__ idxk, const float* __restrict__ uvec,
    const float* __restrict__ ApkT, const float* __restrict__ bnp,
    int M, int Trow, int Tcomp)
{
  __shared__ __align__(8) float xks[4][100];
  __shared__ __align__(8) float yks[4][100];
  int tid = threadIdx.x;
  int g = tid >> 6, lane = tid & 63;
  int m = blockIdx.x*4 + g;
  bool act = (m < M);
  float s = 0.f, sk = 0.f;
  if (act){
    int mrow = (m/Tcomp)*Trow + (m%Tcomp);
    const bfu* xr = X + (long)mrow*NN;
    #pragma unroll
    for (int q = 0; q < 12; ++q){
      int v = lane + q*64;
      if (v < NN) s += b2f(xr[v]);
    }
    for (int o = 32; o; o >>= 1) s += __shfl_xor(s, o, 64);
    #pragma unroll
    for (int q = 0; q < 2; ++q){
      int k = lane + q*64;
      if (k < 100){
        float v = b2f(xr[idxk[k]]);
        xks[g][k] = v;
        sk += v;
      }
    }
    for (int o = 32; o; o >>= 1) sk += __shfl_xor(sk, o, 64);
  }
  __syncthreads();
  int r0 = lane*2;
  bool ract = act && (r0 < 100);
  float u1val = 0.f, sumY = 0.f;
  if (act){
    int c = (m / Tcomp) & 31;
    float sb = bnp[c*2], bb = bnp[c*2+1];
    u1val = sb*(s*(1.f/716.f)) + bb;
    if (lane == 0) U1[m] = u1val;
    if (ract){
      float2 uv = *(const float2*)(uvec + r0);
      float a0 = uv.x*(s - sk);
      float a1 = uv.y*(s - sk);
      for (int k = 0; k < 100; ++k){
        float2 ap = *(const float2*)(ApkT + k*100 + r0);
        float xv = xks[g][k];
        a0 += ap.x*xv;
        a1 += ap.y*xv;
      }
      bfu y0 = f2b(sb*a0 + bb);
      bfu y1 = f2b(sb*a1 + bb);
      ushort2 yo; yo.x = y0; yo.y = y1;
      *(ushort2*)(Y1k + (long)m*100 + r0) = yo;
      float yf0 = b2f(y0), yf1 = b2f(y1);
      float2 yw; yw.x = yf0; yw.y = yf1;
      *(float2*)&yks[g][r0] = yw;
      sumY = yf0 + yf1;
    }
    for (int o = 32; o; o >>= 1) sumY += __shfl_xor(sumY, o, 64);
  }
  __syncthreads();
  if (!act) return;
  float base = 616.f*u1val;
  if (lane == 0) U2[m] = (base + sumY)*(1.f/716.f);
  if (r0 < 100){
    float2 uv = *(const float2*)(uvec + r0);
    float a0 = uv.x*base;
    float a1 = uv.y*base;
    for (int k = 0; k < 100; ++k){
      float2 ap = *(const float2*)(ApkT + k*100 + r0);
      float yv = yks[g][k];
      a0 += ap.x*yv;
      a1 += ap.y*yv;
    }
    ushort2 yo; yo.x = f2b(a0); yo.y = f2b(a1);
    *(ushort2*)(Y2k + (long)m*100 + r0) = yo;
  }
}

// premix
__global__ __launch_bounds__(256) void k_ymix(const float* __restrict__ U1,
    const float* __restrict__ U2, const bfu* __restrict__ Y1k, const bfu* __restrict__ Y2k,
    const float* __restrict__ pWl, float* __restrict__ V12, float* __restrict__ M12, int Tp)
{
  int t = blockIdx.x, b = blockIdx.y, tid = threadIdx.x;
  __shared__ float w1t[1024], w2t[1024];
  __shared__ float y1s[3200], y2s[3200];
  __shared__ float u1s[32], u2s[32];
  for (int i = tid; i < 1024; i += 256){
    int o = i & 31, c = i >> 5;
    w1t[c*32+o] = pWl[o*96+32+c];
    w2t[c*32+o] = pWl[o*96+64+c];
  }
  for (int i = tid; i < 3200; i += 256){
    int c = i/100, r = i - c*100;
    long m = (long)(b*32+c)*Tp + t;
    y1s[i] = b2f(Y1k[m*100 + r]);
    y2s[i] = b2f(Y2k[m*100 + r]);
  }
  if (tid < 32){
    long m = (long)(b*32+tid)*Tp + t;
    u1s[tid] = U1[m]; u2s[tid] = U2[m];
  }
  __syncthreads();
  for (int i = tid; i < 3200; i += 256){
    int r = i >> 5, o = i & 31;
    float acc = 0.f;
    #pragma unroll 8
    for (int c = 0; c < 32; ++c)
      acc += w1t[c*32+o]*y1s[c*100+r] + w2t[c*32+o]*y2s[c*100+r];
    M12[((long)(b*Tp+t)*100 + r)*32 + o] = acc;
  }
  if (tid < 32){
    float acc = 0.f;
    #pragma unroll 8
    for (int c = 0; c < 32; ++c)
      acc += w1t[c*32+tid]*u1s[c] + w2t[c*32+tid]*u2s[c];
    V12[(long)(b*Tp+t)*32 + tid] = acc;
  }
}

// ---------------- combine + skip + fused BN partials; 2 n/thread ----------------
__global__ __launch_bounds__(256) void k_combine3nc(const bfu* __restrict__ x,
    bfu* __restrict__ F, const int* __restrict__ rankv,
    const float* __restrict__ M12, const float* __restrict__ V12,
    const float* __restrict__ pWl, const float* __restrict__ pbl,
    const float* __restrict__ skWl, const float* __restrict__ skbl,
    const float* __restrict__ alpha, const float* __restrict__ bnp,
    bfu* __restrict__ skipP, float* __restrict__ bnred,
    int T, int Tp, int d, int off2)
{
  __shared__ float w0t[1024];
  __shared__ bfu Msb[101*34];      // bf16, stride 34 (bank spread on sel)
  __shared__ float swt[256], bnl[64], pbs[32], sb8[8];
  int tid = threadIdx.x;
  int tot2 = 2*Tp;
  int L = blockIdx.x + 2*(blockIdx.y + Tp*blockIdx.z);
  int xcd = L & 7, slot = L >> 3;
  int b = xcd + ((slot/tot2) << 3);
  int r2 = slot - (slot/tot2)*tot2;
  int t = r2/2, bx2 = r2 & 1;
  for (int i = tid; i < 1024; i += 256){
    int o = i & 31, c = i >> 5;
    w0t[c*32+o] = pWl[o*96+c];
  }
  for (int i = tid; i < 3434; i += 256){
    int r = i/34, o = i - r*34;
    if (o < 32)
      Msb[r*34+o] = f2b((r < 100) ? M12[((long)(b*Tp+t)*100 + r)*32 + o]
                                  : V12[(long)(b*Tp+t)*32 + o]);
  }
  swt[tid] = skWl[tid];
  if (tid < 64) bnl[tid] = bnp[tid];
  if (tid < 32) pbs[tid] = pbl[tid];
  if (tid < 8)  sb8[tid] = skbl[tid];
  __syncthreads();
  int n = bx2*512 + tid*2;
  bool act = (n < NN);
  float ax[32], ay[32];
  #pragma unroll
  for (int o = 0; o < 32; ++o){ ax[o] = pbs[o]; ay[o] = pbs[o]; }
  const float4* w04 = (const float4*)w0t;
  if (act){
    #pragma unroll 2
    for (int c = 0; c < 32; ++c){
      float sc = bnl[c*2], bc = bnl[c*2+1];
      ushort2 xv = *(const ushort2*)(x + ((long)(b*32+c)*T + t)*NN + n);
      float x0 = b2f(xv.x)*sc + bc;
      float x1 = b2f(xv.y)*sc + bc;
      #pragma unroll
      for (int o4 = 0; o4 < 8; ++o4){
        float4 w = w04[c*8+o4];
        ax[o4*4+0] += w.x*x0;  ay[o4*4+0] += w.x*x1;
        ax[o4*4+1] += w.y*x0;  ay[o4*4+1] += w.y*x1;
        ax[o4*4+2] += w.z*x0;  ay[o4*4+2] += w.z*x1;
        ax[o4*4+3] += w.w*x0;  ay[o4*4+3] += w.w*x1;
      }
    }
  }
  int ra = act ? rankv[n]   : -1;
  int rb = act ? rankv[n+1] : -1;
  int sela = (ra < 0) ? 100 : ra;
  int selb = (rb < 0) ? 100 : rb;
  float a_s = sigmoidf_(alpha[0]);
  #pragma unroll
  for (int o = 0; o < 32; ++o){
    float v0 = 0.f, v1 = 0.f;
    if (act){
      float scb = bnl[o*2], bcb = bnl[o*2+1];
      long oidx = ((long)(b*32+o)*Tp + t)*NN + n;
      ushort2 gv = *(const ushort2*)(F + oidx);
      ushort2 rv = *(const ushort2*)(x + ((long)(b*32+o)*T + t + d)*NN + n);
      v0 = a_s*(ax[o] + b2f(Msb[sela*34+o])) + b2f(gv.x) + b2f(rv.x)*scb + bcb;
      v1 = a_s*(ay[o] + b2f(Msb[selb*34+o])) + b2f(gv.y) + b2f(rv.y)*scb + bcb;
      ushort2 ov; ov.x = f2b(v0); ov.y = f2b(v1);
      *(ushort2*)(F + oidx) = ov;
    }
    ax[o] = v0; ay[o] = v1;
  }
  {
    int wave = tid >> 6;
    int gid = ((blockIdx.x + gridDim.x*(blockIdx.y + gridDim.y*blockIdx.z)) << 2) + wave;
    #pragma unroll
    for (int o = 0; o < 32; ++o){
      float v  = ax[o] + ay[o];
      float vq = ax[o]*ax[o] + ay[o]*ay[o];
      for (int s = 32; s; s >>= 1){
        v  += __shfl_xor(v,  s, 64);
        vq += __shfl_xor(vq, s, 64);
      }
      if ((tid & 63) == 0){
        bnred[((long)o*MAXG + gid)*2]     = v;
        bnred[((long)o*MAXG + gid)*2 + 1] = vq;
      }
    }
  }
  if (!act) return;
  const float4* sw4 = (const float4*)swt;
  #pragma unroll
  for (int sc2 = 0; sc2 < 8; ++sc2){
    float s0 = sb8[sc2], s1 = sb8[sc2];
    #pragma unroll
    for (int c4 = 0; c4 < 8; ++c4){
      float4 w = sw4[sc2*8 + c4];
      s0 += w.x*ax[c4*4] + w.y*ax[c4*4+1] + w.z*ax[c4*4+2] + w.w*ax[c4*4+3];
      s1 += w.x*ay[c4*4] + w.y*ay[c4*4+1] + w.z*ay[c4*4+2] + w.w*ay[c4*4+3];
    }
    ushort2 ov; ov.x = f2b(fmaxf(s0, 0.f)); ov.y = f2b(fmaxf(s1, 0.f));
    *(ushort2*)(skipP + ((long)b*416 + off2 + t*8 + sc2)*NN + n) = ov;
  }
}

// reduce per-wave BN partials -> bnp
__global__ void k_bn2v2(const float* __restrict__ red, const float* __restrict__ gamma,
                        const float* __restrict__ beta, float* __restrict__ bnp,
                        int layer, int Tp, int ngroups){
  int c = blockIdx.x, tid = threadIdx.x;
  float s = 0.f, s2 = 0.f;
  for (int g = tid; g < ngroups; g += 256){
    s  += red[((long)c*MAXG + g)*2];
    s2 += red[((long)c*MAXG + g)*2 + 1];
  }
  __shared__ float rs[256], rs2[256];
  rs[tid] = s; rs2[tid] = s2; __syncthreads();
  for (int k = 128; k > 0; k >>= 1){
    if (tid < k){ rs[tid] += rs[tid+k]; rs2[tid] += rs2[tid+k]; }
    __syncthreads();
  }
  if (tid == 0){
    float cnt = 64.f*Tp*716.f;
    float mu = rs[0]/cnt, var = rs2[0]/cnt - mu*mu;
    float rstd = rsqrtf(var + 1e-5f);
    float ga = gamma[layer*32+c], be = beta[layer*32+c];
    bnp[c*2] = rstd*ga; bnp[c*2+1] = be - mu*rstd*ga;
  }
}

// ---------------- end MLP ----------------

__global__ __launch_bounds__(256) void k_sktr(const bfu* __restrict__ SP, bfu* __restrict__ ST){
  __shared__ bfu tile[64][66];
  int b = blockIdx.z;
  int n0 = blockIdx.x*64, k0 = blockIdx.y*64;
  int tid = threadIdx.x;
  int tr = tid >> 6, tc = tid & 63;
  #pragma unroll
  for (int p = 0; p < 16; ++p){
    int k = k0 + p*4 + tr, n = n0 + tc;
    tile[p*4+tr][tc] = (k < 416 && n < NN) ? SP[((long)b*416 + k)*NN + n] : (bfu)0;
  }
  __syncthreads();
  #pragma unroll
  for (int p = 0; p < 16; ++p){
    int n = n0 + p*4 + tr, k = k0 + tc;
    if (n < NN && k < 416) ST[((long)b*NN + n)*416 + k] = tile[tc][p*4+tr];
  }
}

__global__ __launch_bounds__(256) void k_end2(const bfu* __restrict__ H,
    const float* __restrict__ W2, const float* __restrict__ b2, float* __restrict__ out)
{
  __shared__ float w[12*512];
  for (int i = threadIdx.x; i < 6144; i += 256) w[i] = W2[i];
  __syncthreads();
  int n = blockIdx.x*256 + threadIdx.x; if (n >= NN) return;
  int b = blockIdx.y;
  float acc[12];
  #pragma unroll
  for (int o = 0; o < 12; ++o) acc[o] = b2[o];
  for (int e = 0; e < 512; ++e){
    float h = b2f(H[((long)b*512+e)*NN + n]);
    #pragma unroll
    for (int o = 0; o < 12; ++o) acc[o] += w[o*512+e]*h;
  }
  #pragma unroll
  for (int o = 0; o < 12; ++o) out[((long)b*12+o)*NN + n] = acc[o];
}

// ---------------- launch ----------------

extern "C" void kernel_launch(void* const* d_in, const int* in_sizes, int n_in,
                              void* d_out, int out_size, void* d_ws, size_t ws_size,
                              hipStream_t stream)
{
  const float* hist = (const float*)d_in[0];
  const float* alpha = (const float*)d_in[1];
  const float* p1  = (const float*)d_in[2];
  const float* p2  = (const float*)d_in[3];
  const float* p3  = (const float*)d_in[4];
  const float* pk  = (const float*)d_in[5];
  const float* piv = (const float*)d_in[6];
  const float* sW  = (const float*)d_in[7];
  const float* sb  = (const float*)d_in[8];
  const float* saW = (const float*)d_in[9];
  const float* sab = (const float*)d_in[10];
  const float* fW  = (const float*)d_in[11];
  const float* fb  = (const float*)d_in[12];
  const float* gW  = (const float*)d_in[13];
  const float* gb  = (const float*)d_in[14];
  const float* skW = (const float*)d_in[15];
  const float* skb = (const float*)d_in[16];
  const float* gcW = (const float*)d_in[17];
  const float* gcb = (const float*)d_in[18];
  const float* pgW = (const float*)d_in[19];
  const float* pgb = (const float*)d_in[20];
  const float* bng = (const float*)d_in[21];
  const float* bnb = (const float*)d_in[22];
  const float* e1W = (const float*)d_in[23];
  const float* e1b = (const float*)d_in[24];
  const float* e2W = (const float*)d_in[25];
  const float* e2b = (const float*)d_in[26];
  float* out = (float*)d_out;

  char* base = (char*)d_ws;
  size_t off = 0;
  auto alloc = [&](size_t bytes)->char*{
    char* r = base + off;
    off = (off + bytes + 255) & ~(size_t)255;
    return r;
  };
  const size_t SZ12 = 64UL*32*12*716*2;
  const size_t SZ13 = 64UL*32*13*716*2;
  bfu*   t1    = (bfu*)  alloc(SZ12);
  bfu*   t2    = (bfu*)  alloc(SZ12);
  bfu*   P     = (bfu*)  alloc(SZ13);
  bfu*   Q     = (bfu*)  alloc(SZ12);
  bfu*   skipP = (bfu*)  alloc(64UL*416*716*2);
  bfu*   skipT = (bfu*)  alloc(64UL*716*416*2);
  float* adjp  = (float*)alloc((size_t)NSQ*4);
  float* tmp1  = (float*)alloc(64UL*1600*4);
  float* tmp2  = (float*)alloc(64UL*716*40*4);
  float* p3t   = (float*)alloc(40UL*716*4);
  bfu*   e1Wb  = (bfu*)  alloc(512UL*416*2);
  unsigned int* topA = (unsigned int*)alloc(64UL*NN*16*4);
  int*   cntA  = (int*)  alloc(64UL*NN*4);
  float* xs    = (float*)alloc(716UL*13*4);
  float* yv    = (float*)alloc(716UL*4);
  float* score = (float*)alloc(716UL*4);
  float* bnred = (float*)alloc(32UL*MAXG*2*4);
  float* bnp   = (float*)alloc(64UL*4);
  float* bnpid = (float*)alloc(64UL*4);
  float* uvec  = (float*)alloc(100UL*4);
  float* ApkT  = (float*)alloc(100UL*100*4);
  int*   ind   = (int*)  alloc(64UL*4);
  int*   mask  = (int*)  alloc(716UL*4);
  int*   idxk  = (int*)  alloc(100UL*4);
  int*   rankv = (int*)  alloc(716UL*4);

  // pgcn-compact buffers aliased INTO t1 (dead between k_xgmix_mfma and next gather)
  char* t1c = (char*)t1;
  float* U1  = (float*)(t1c);
  float* U2  = (float*)(t1c +   98304);
  float* V12 = (float*)(t1c + 2*98304);
  float* M12 = (float*)(t1c + 3*98304);
  bfu*   Y1k = (bfu*)  (t1c + 3*98304 + 9830400);
  bfu*   Y2k = (bfu*)  (t1c + 3*98304 + 9830400 + 4915200);

  bfu* hidden = t1;

  // dynamic adjacency (sparse capture)
  k_ind<<<1,64,0,stream>>>(hist, ind);
  k_dg1<<<64,256,0,stream>>>(p1, pk, ind, tmp1);
  k_dg2<<<dim3(112,64),256,0,stream>>>(p2, tmp1, tmp2);
  k_p3t<<<3,256,0,stream>>>(p3, p3t);
  k_adjrow4s<<<dim3(179,64),256,0,stream>>>(p3t, tmp2, topA, cntA);
  // pivotal adjacency (compact structure)
  k_xs<<<716,64,0,stream>>>(hist, saW, sab, xs, yv);
  k_adjp<<<dim3(3,716),256,0,stream>>>(xs, yv, piv, adjp);
  k_score<<<716,256,0,stream>>>(adjp, score);
  k_topk<<<1,256,0,stream>>>(score, mask);
  k_pivprep<<<1,256,0,stream>>>(adjp, mask, idxk, rankv, uvec, ApkT);
  // start conv + weight conversion + identity BN
  k_init_x<<<dim3(3,13,64),256,0,stream>>>(hist, sW, sb, P);
  k_e1perm<<<(512*416+255)/256,256,0,stream>>>(e1W, e1Wb);
  k_bnid<<<1,64,0,stream>>>(bnpid);

  int T = 13;
  bfu* x = P;
  bfu* F = Q;
  static const int off2_[8] = {0,96,176,248,304,352,384,408};
  for (int i = 0; i < 8; ++i){
    int d = (i & 1) ? 2 : 1;
    int Tp = T - d;
    const float* bnin = (i == 0) ? bnpid : bnp;
    dim3 g2n(2, Tp, 64);
    dim3 g6(6, Tp, 64);
    // MFMA gated conv, BN folded in-block
    k_fg_mfma<<<g6,256,0,stream>>>(x, fW + i*2048, fb + i*32, gW + i*2048, gb + i*32,
        bnin, F, T, Tp, d);
    // xg path: fused double sparse diffusion then MFMA channel-mix over F
    int M1 = 32*Tp; long sx1 = (long)M1*NN;
    dim3 gz((M1+3)/4, 64);
    k_zgather2<<<gz,256,0,stream>>>(F, topA, cntA, t1, t2, M1, sx1);
    k_xgmix_mfma<<<g6,256,0,stream>>>(F, t1, t2, gcW + i*3072, gcb + i*32, alpha, Tp);
    // pgcn path, compact (fused 1st+2nd diffusion; buffers live in dead t1)
    int M2 = 64*32*Tp;
    k_pgdiff12<<<M2/4,256,0,stream>>>(x, U1, Y1k, U2, Y2k, idxk, uvec, ApkT, bnin,
        M2, T, Tp);
    k_ymix<<<dim3(Tp,64),256,0,stream>>>(U1, U2, Y1k, Y2k, pgW + i*3072, V12, M12, Tp);
    // combine + residual + skip + fused BN partials (2 n/thread)
    k_combine3nc<<<g2n,256,0,stream>>>(x, F, rankv, M12, V12, pgW + i*3072, pgb + i*32,
        skW + i*256, skb + i*8, alpha, bnin, skipP, bnred, T, Tp, d, off2_[i]);
    int ngroups = 2*Tp*64*4;
    k_bn2v2<<<32,256,0,stream>>>(bnred, bng, bnb, bnp, i, Tp, ngroups);
    bfu* tmp = x; x = F; F = tmp;
    T = Tp;
  }
  // end MLP
  k_sktr<<<dim3(12,7,64),256,0,stream>>>(skipP, skipT);
  gemm_mfma<<<dim3(6,4,64),256,0,stream>>>(e1Wb, skipT, hidden, 512, 416,
      0L, 416L*716, 512L*716, e1b, 1, 1, 1);
  k_end2<<<dim3(3,64),256,0,stream>>>(hidden, e2W, e2b, out);
}

// Round 23
// 2512.052 us; speedup vs baseline: 1.1483x; 1.1105x over previous
//
#include <hip/hip_runtime.h>
#include <math.h>

#define NN 716
#define NSQ (716*716)
#define MAXG 9216
#define FPAD 70
#define XPAD 102
typedef unsigned short bfu;
typedef __attribute__((ext_vector_type(8))) __bf16 bf16x8;
typedef __attribute__((ext_vector_type(4))) float f32x4;

__device__ __forceinline__ float b2f(bfu u){ union{unsigned int i; float f;} x; x.i = ((unsigned int)u)<<16; return x.f; }
__device__ __forceinline__ bfu f2b(float f){ union{float fv; unsigned int i;} x; x.fv = f; unsigned int r = (x.i + 0x7fffu + ((x.i>>16)&1u)) >> 16; return (bfu)r; }
__device__ __forceinline__ float sigmoidf_(float x){ return 1.f/(1.f+expf(-x)); }

__device__ __forceinline__ float fexp_(float x){
#if __has_builtin(__builtin_amdgcn_exp2f)
  return __builtin_amdgcn_exp2f(x * 1.44269504088896340736f);
#else
  return __expf(x);
#endif
}
__device__ __forceinline__ float frcp_(float x){
#if __has_builtin(__builtin_amdgcn_rcpf)
  return __builtin_amdgcn_rcpf(x);
#else
  return 1.f/x;
#endif
}
__device__ __forceinline__ float fsig_(float x){ return frcp_(1.f + fexp_(-x)); }
__device__ __forceinline__ float ftanh_(float x){
  float xc = fminf(fmaxf(x, -30.f), 30.f);
  float e = fexp_(-2.f*xc);
  return (1.f - e) * frcp_(1.f + e);
}

// ---------------- init / adjacency construction ----------------

__global__ void k_ind(const float* __restrict__ hist, int* __restrict__ ind){
  int b = threadIdx.x; if (b >= 64) return;
  float v = hist[((b*12+11)*NN + 0)*2 + 1];
  ind[b] = ((int)(v*288.0f)) % 288;
}

__global__ void k_dg1(const float* __restrict__ p1, const float* __restrict__ pk,
                      const int* __restrict__ ind, float* __restrict__ tmp1){
  int b = blockIdx.x;
  __shared__ float p1s[40];
  if (threadIdx.x < 40) p1s[threadIdx.x] = p1[ind[b]*40 + threadIdx.x];
  __syncthreads();
  for (int jk = threadIdx.x; jk < 1600; jk += 256){
    float acc = 0.f;
    for (int i = 0; i < 40; ++i) acc += p1s[i]*pk[i*1600 + jk];
    tmp1[b*1600 + jk] = acc;
  }
}

__global__ void k_dg2(const float* __restrict__ p2, const float* __restrict__ tmp1,
                      float* __restrict__ tmp2){
  int b = blockIdx.y;
  __shared__ float ts[1600];
  for (int i = threadIdx.x; i < 1600; i += 256) ts[i] = tmp1[b*1600+i];
  __syncthreads();
  int idx = blockIdx.x*256 + threadIdx.x;
  if (idx >= NN*40) return;
  int n = idx/40, k = idx%40;
  float acc = 0.f;
  for (int j = 0; j < 40; ++j) acc += p2[n*40+j]*ts[j*40+k];
  tmp2[(long)b*NN*40 + idx] = acc;
}

__global__ void k_p3t(const float* __restrict__ p3, float* __restrict__ p3t){
  int v = blockIdx.x*256 + threadIdx.x; if (v >= NN) return;
  for (int k = 0; k < 40; ++k) p3t[k*NN + v] = p3[v*40 + k];
}

// 4 adjacency rows per block: logits -> relu -> softmax -> SPARSE top-16 capture
__global__ __launch_bounds__(256) void k_adjrow4s(const float* __restrict__ p3t,
    const float* __restrict__ tmp2, unsigned int* __restrict__ topA,
    int* __restrict__ cntA)
{
  int b = blockIdx.y, w0 = blockIdx.x*4, tid = threadIdx.x;
  int wave = tid >> 6, lane = tid & 63;
  __shared__ float t2s[4][40];
  __shared__ float buf[4][720];
  __shared__ float wred[4][4];
  __shared__ float rstat[4];
  __shared__ int pc[4][12];
  for (int i = tid; i < 160; i += 256){
    int r = i/40, k = i%40; int w = w0 + r;
    t2s[r][k] = (w < NN) ? tmp2[((long)b*NN + w)*40 + k] : 0.f;
  }
  __syncthreads();
  float lmax[4] = {0,0,0,0};
  for (int q = 0; q < 3; ++q){
    int v = tid + q*256;
    if (v < NN){
      float a[4] = {0,0,0,0};
      #pragma unroll 8
      for (int k = 0; k < 40; ++k){
        float pv = p3t[k*NN + v];
        #pragma unroll
        for (int r = 0; r < 4; ++r) a[r] += t2s[r][k]*pv;
      }
      #pragma unroll
      for (int r = 0; r < 4; ++r){
        float val = fmaxf(a[r], 0.f);
        buf[r][v] = val;
        lmax[r] = fmaxf(lmax[r], val);
      }
    }
  }
  #pragma unroll
  for (int r = 0; r < 4; ++r){
    float m = lmax[r];
    for (int s = 32; s > 0; s >>= 1) m = fmaxf(m, __shfl_xor(m, s, 64));
    if (lane == 0) wred[r][wave] = m;
  }
  __syncthreads();
  if (tid < 4) rstat[tid] = fmaxf(fmaxf(wred[tid][0], wred[tid][1]), fmaxf(wred[tid][2], wred[tid][3]));
  __syncthreads();
  float lsum[4] = {0,0,0,0};
  for (int q = 0; q < 3; ++q){
    int v = tid + q*256;
    if (v < NN){
      #pragma unroll
      for (int r = 0; r < 4; ++r){
        float e = fexp_(buf[r][v] - rstat[r]);
        buf[r][v] = e;
        lsum[r] += e;
      }
    }
  }
  __syncthreads();
  #pragma unroll
  for (int r = 0; r < 4; ++r){
    float s = lsum[r];
    for (int k = 32; k > 0; k >>= 1) s += __shfl_xor(s, k, 64);
    if (lane == 0) wred[r][wave] = s;
  }
  __syncthreads();
  if (tid < 4) rstat[tid] = frcp_(wred[tid][0] + wred[tid][1] + wred[tid][2] + wred[tid][3]);
  __syncthreads();
  for (int q = 0; q < 3; ++q){
    int v = tid + q*256;
    #pragma unroll
    for (int r = 0; r < 4; ++r){
      float p = (v < NN) ? buf[r][v]*rstat[r] : 0.f;
      unsigned long long m = __ballot(p >= 1e-7f);
      if (lane == 0) pc[r][q*4+wave] = __popcll(m);
    }
  }
  __syncthreads();
  for (int q = 0; q < 3; ++q){
    int v = tid + q*256;
    #pragma unroll
    for (int r = 0; r < 4; ++r){
      float p = (v < NN) ? buf[r][v]*rstat[r] : 0.f;
      bool qual = (p >= 1e-7f);
      unsigned long long m = __ballot(qual);
      int w = w0 + r;
      if (qual && w < NN){
        int base = 0, me = q*4+wave;
        for (int s = 0; s < me; ++s) base += pc[r][s];
        unsigned long long below = (lane == 0) ? 0ull : (m << (64-lane) >> (64-lane));
        int pos = base + __popcll(below);
        if (pos < 16)
          topA[((long)b*NN + w)*16 + pos] = (((unsigned)v)<<16) | (unsigned)f2b(p);
      }
    }
  }
  __syncthreads();
  if (tid < 4){
    int w = w0 + tid;
    if (w < NN){
      int tot = 0;
      for (int s = 0; s < 12; ++s) tot += pc[tid][s];
      cntA[(long)b*NN + w] = (tot < 16) ? tot : 16;
    }
  }
}

// fused double sparse diffusion: z1[m] = A-gather(X[m]); z2[m] = A-gather(z1[m])
__global__ __launch_bounds__(256) void k_zgather2(const bfu* __restrict__ Xg,
    const unsigned int* __restrict__ topA, const int* __restrict__ cntA,
    bfu* __restrict__ Z1g, bfu* __restrict__ Z2g, int M, long sx)
{
  __shared__ bfu rows[4][720];
  __shared__ bfu zrow[4][720];
  int b = blockIdx.y;
  int tid = threadIdx.x, wave = tid >> 6, lane = tid & 63;
  int m = blockIdx.x*4 + wave;
  if (m < M){
    const bfu* xr = Xg + (long)b*sx + (long)m*NN;
    #pragma unroll
    for (int q = 0; q < 12; ++q){
      int v = lane + q*64;
      if (v < NN) rows[wave][v] = xr[v];
    }
  }
  __syncthreads();
  const unsigned int* ta = topA + (long)b*NN*16;
  const int* ca = cntA + (long)b*NN;
  if (m < M){
    bfu* zr = Z1g + (long)b*sx + (long)m*NN;
    #pragma unroll
    for (int q = 0; q < 12; ++q){
      int w = lane + q*64;
      if (w < NN){
        int cnt = ca[w];
        const unsigned int* lst = ta + (long)w*16;
        float acc = 0.f;
        for (int j = 0; j < cnt; ++j){
          unsigned int e = lst[j];
          acc += b2f((bfu)(e & 0xffffu)) * b2f(rows[wave][e >> 16]);
        }
        bfu zv = f2b(acc);
        zr[w] = zv;
        zrow[wave][w] = zv;
      }
    }
  }
  __syncthreads();
  if (m >= M) return;
  bfu* z2r = Z2g + (long)b*sx + (long)m*NN;
  #pragma unroll
  for (int q = 0; q < 12; ++q){
    int w = lane + q*64;
    if (w < NN){
      int cnt = ca[w];
      const unsigned int* lst = ta + (long)w*16;
      float acc = 0.f;
      for (int j = 0; j < cnt; ++j){
        unsigned int e = lst[j];
        acc += b2f((bfu)(e & 0xffffu)) * b2f(zrow[wave][e >> 16]);
      }
      z2r[w] = f2b(acc);
    }
  }
}

// xs[n][t] = sum_b x_a[b,n,t]; y[n] = sum_t xs[n][t]
__global__ void k_xs(const float* __restrict__ hist, const float* __restrict__ saW,
                     const float* __restrict__ sab, float* __restrict__ xs, float* __restrict__ y){
  int n = blockIdx.x, b = threadIdx.x; // 64 threads
  float w = saW[0], bb = sab[0];
  float ytot = 0.f;
  for (int t = 0; t < 13; ++t){
    float inp = (t == 0) ? 0.f : hist[((b*12 + (t-1))*NN + n)*2];
    float s = inp;
    for (int off = 32; off > 0; off >>= 1) s += __shfl_down(s, off, 64);
    if (b == 0){ float val = w*s + 64.f*bb; xs[n*13+t] = val; ytot += val; }
  }
  if (b == 0) y[n] = ytot;
}

__global__ void k_adjp(const float* __restrict__ xs, const float* __restrict__ y,
                       const float* __restrict__ piv, float* __restrict__ adjp){
  int i = blockIdx.y;
  __shared__ float xi[13];
  if (threadIdx.x < 13) xi[threadIdx.x] = xs[i*13+threadIdx.x];
  __syncthreads();
  int j = blockIdx.x*256 + threadIdx.x;
  if (j >= NN) return;
  float acc = 0.f;
  #pragma unroll
  for (int t = 0; t < 12; ++t) acc += xi[t]*xs[j*13+t+1];
  adjp[(long)i*NN+j] = acc / y[j] * piv[(long)i*NN+j];
}

__global__ void k_score(const float* __restrict__ adjp, float* __restrict__ score){
  int n = blockIdx.x, tid = threadIdx.x;
  float s = 0.f;
  for (int i = tid; i < NN; i += 256) s += adjp[(long)i*NN+n] + adjp[(long)n*NN+i];
  __shared__ float red[256];
  red[tid] = s; __syncthreads();
  for (int k = 128; k > 0; k >>= 1){ if (tid < k) red[tid] += red[tid+k]; __syncthreads(); }
  if (tid == 0) score[n] = red[0];
}

// bitonic sort 1024 (desc, tie->lower index first), take top 100 -> mask
__global__ void k_topk(const float* __restrict__ score, int* __restrict__ mask){
  __shared__ float v[1024];
  __shared__ int ix[1024];
  int tid = threadIdx.x;
  for (int t = tid; t < 1024; t += 256){ v[t] = (t < NN) ? score[t] : -INFINITY; ix[t] = t; }
  __syncthreads();
  for (int k = 2; k <= 1024; k <<= 1){
    for (int j = k >> 1; j > 0; j >>= 1){
      for (int t = tid; t < 1024; t += 256){
        int l = t ^ j;
        if (l > t){
          bool up = ((t & k) == 0);
          bool g = (v[t] > v[l]) || (v[t] == v[l] && ix[t] < ix[l]);
          if (up ? !g : g){
            float tv = v[t]; v[t] = v[l]; v[l] = tv;
            int ti = ix[t]; ix[t] = ix[l]; ix[l] = ti;
          }
        }
      }
      __syncthreads();
    }
  }
  for (int t = tid; t < NN; t += 256) mask[t] = 0;
  __syncthreads();
  if (tid < 100) mask[ix[tid]] = 1;
}

// build compact pivotal structure: idx[100], rank[716], u[100], ApkT[100k][100r]
__global__ void k_pivprep(const float* __restrict__ adjp, const int* __restrict__ mask,
                          int* __restrict__ idxk, int* __restrict__ rankv,
                          float* __restrict__ uvec, float* __restrict__ ApkT){
  __shared__ int sidx[100];
  int tid = threadIdx.x;
  if (tid == 0){
    int c = 0;
    for (int i = 0; i < NN; ++i){
      if (mask[i] && c < 100){ sidx[c] = i; idxk[c] = i; rankv[i] = c; ++c; }
      else rankv[i] = -1;
    }
  }
  __syncthreads();
  if (tid < 100){
    int i = sidx[tid];
    const float* row = adjp + (long)i*NN;
    float mx = 0.f;
    for (int k = 0; k < 100; ++k) mx = fmaxf(mx, row[sidx[k]]);
    float sum = 616.f * fexp_(-mx);
    for (int k = 0; k < 100; ++k) sum += fexp_(fmaxf(row[sidx[k]], 0.f) - mx);
    float inv = 1.f/sum;
    uvec[tid] = fexp_(-mx)*inv;
    for (int k = 0; k < 100; ++k)
      ApkT[k*100 + tid] = fexp_(fmaxf(row[sidx[k]], 0.f) - mx)*inv;
  }
}

// x[b,c,t,n] = start_W[c]*inp + start_b[c]
__global__ void k_init_x(const float* __restrict__ hist, const float* __restrict__ sW,
                         const float* __restrict__ sb, bfu* __restrict__ x){
  int n = blockIdx.x*256 + threadIdx.x; if (n >= NN) return;
  int t = blockIdx.y, b = blockIdx.z;
  float inp = (t == 0) ? 0.f : hist[((b*12 + (t-1))*NN + n)*2];
  #pragma unroll
  for (int c = 0; c < 32; ++c)
    x[((long)(b*32+c)*13 + t)*NN + n] = f2b(sW[c]*inp + sb[c]);
}

// identity BN params
__global__ void k_bnid(float* __restrict__ bnp){
  int c = threadIdx.x; if (c >= 32) return;
  bnp[c*2] = 1.f; bnp[c*2+1] = 0.f;
}

// permuted e1W -> bf16
__global__ void k_e1perm(const float* __restrict__ W, bfu* __restrict__ Wb){
  int i = blockIdx.x*256 + threadIdx.x;
  if (i >= 512*416) return;
  int e = i/416, kp = i%416;
  const int off2[9] = {0,96,176,248,304,352,384,408,416};
  const int soff[8] = {320,240,168,112,64,32,8,0};
  const int tpl[8]  = {12,10,9,7,6,4,3,1};
  int L = 0;
  #pragma unroll
  for (int q = 0; q < 8; ++q) if (kp >= off2[q+1]) L = q+1;
  int r = kp - off2[L]; int t = r>>3, sc = r&7;
  int k = soff[L] + sc*tpl[L] + t;
  Wb[e*416+kp] = f2b(W[e*416+k]);
}

// ---------------- MFMA GEMM (end1 only) ----------------
#define LDST 44

__global__ __launch_bounds__(256) void gemm_mfma(const bfu* __restrict__ Xg,
    const bfu* __restrict__ Ag, bfu* __restrict__ Cg,
    int M, int K, long sx, long sa, long sc,
    const float* __restrict__ bias, int relu_out, int Trow, int Tcomp)
{
  int bx = gridDim.x, by = gridDim.y, nb = gridDim.z;
  int bX = blockIdx.x, bY = blockIdx.y, bZ = blockIdx.z;
  int bpb = bx*by, total = bpb*nb;
  if ((total & 7) == 0 && (nb & 7) == 0){
    int L = bX + bx*(bY + by*bZ);
    int xcd = L & 7, slot = L >> 3;
    bZ = xcd*(nb >> 3) + slot/bpb;
    int inner = slot % bpb;
    bX = inner % bx; bY = inner / bx;
  }
  const bfu* X = Xg + (long)bZ*sx;
  const bfu* A = Ag + (long)bZ*sa;
  bfu*       C = Cg + (long)bZ*sc;
  int m0 = bY*128, n0 = bX*128;
  __shared__ bfu Xs[128*LDST];
  __shared__ bfu As[128*LDST];
  int tid = threadIdx.x;
  int wave = tid >> 6, lane = tid & 63;
  int wm = (wave >> 1)*64, wn = (wave & 1)*64;
  int lr = lane & 15, lg = lane >> 4;
  f32x4 acc[4][4] = {};
  int ldr = tid >> 1, ldk = (tid & 1)*16;
  int mg = m0 + ldr, ng = n0 + ldr;
  int mrow = (Trow == Tcomp) ? mg : (mg/Tcomp)*Trow + (mg%Tcomp);
  const bfu* xrow = X + (long)mrow*K;
  const bfu* arow = A + (long)ng*K;
  for (int k0 = 0; k0 < K; k0 += 32){
    int kk = k0 + ldk;
    ushort4 z4 = {0,0,0,0};
    ushort4 x0=z4,x1=z4,x2=z4,x3=z4, a0=z4,a1=z4,a2=z4,a3=z4;
    if (mg < M){
      if (kk + 16 <= K){
        const ushort4* s = (const ushort4*)(xrow + kk);
        x0=s[0]; x1=s[1]; x2=s[2]; x3=s[3];
      } else {
        bfu tv[16];
        #pragma unroll
        for (int j=0;j<16;++j) tv[j] = (kk+j < K) ? xrow[kk+j] : (bfu)0;
        const ushort4* s = (const ushort4*)tv;
        x0=s[0]; x1=s[1]; x2=s[2]; x3=s[3];
      }
    }
    if (ng < NN){
      if (kk + 16 <= K){
        const ushort4* s = (const ushort4*)(arow + kk);
        a0=s[0]; a1=s[1]; a2=s[2]; a3=s[3];
      } else {
        bfu tv[16];
        #pragma unroll
        for (int j=0;j<16;++j) tv[j] = (kk+j < K) ? arow[kk+j] : (bfu)0;
        const ushort4* s = (const ushort4*)tv;
        a0=s[0]; a1=s[1]; a2=s[2]; a3=s[3];
      }
    }
    ushort4* xd = (ushort4*)&Xs[ldr*LDST + ldk];
    xd[0]=x0; xd[1]=x1; xd[2]=x2; xd[3]=x3;
    ushort4* ad = (ushort4*)&As[ldr*LDST + ldk];
    ad[0]=a0; ad[1]=a1; ad[2]=a2; ad[3]=a3;
    __syncthreads();
    bf16x8 af[4], bfr[4];
    #pragma unroll
    for (int i=0;i<4;++i){
      af[i]  = *(const bf16x8*)&Xs[(wm + i*16 + lr)*LDST + lg*8];
      bfr[i] = *(const bf16x8*)&As[(wn + i*16 + lr)*LDST + lg*8];
    }
    #pragma unroll
    for (int i=0;i<4;++i)
      #pragma unroll
      for (int j=0;j<4;++j)
        acc[i][j] = __builtin_amdgcn_mfma_f32_16x16x32_bf16(af[i], bfr[j], acc[i][j], 0,0,0);
    __syncthreads();
  }
  #pragma unroll
  for (int i=0;i<4;++i){
    #pragma unroll
    for (int r=0;r<4;++r){
      int m = m0 + wm + i*16 + lg*4 + r;
      if (m >= M) continue;
      float bv = bias ? bias[m] : 0.f;
      #pragma unroll
      for (int j=0;j<4;++j){
        int n = n0 + wn + j*16 + lr;
        if (n < NN){
          float v = acc[i][j][r] + bv;
          if (relu_out) v = fmaxf(v, 0.f);
          C[(long)m*NN + n] = f2b(v);
        }
      }
    }
  }
}

// ---------------- MFMA gated temporal conv (128 n / block, XCD-grouped, BN-folded in-block) ----------------
__global__ __launch_bounds__(256) void k_fg_mfma(const bfu* __restrict__ x,
    const float* __restrict__ fWl, const float* __restrict__ fbl,
    const float* __restrict__ gWl, const float* __restrict__ gbl,
    const float* __restrict__ bnp, bfu* __restrict__ fg, int T, int Tp, int d)
{
  __shared__ bfu Bsh[128*FPAD];
  __shared__ bfu Ash[64*FPAD];
  __shared__ float bsh[64];
  int tid = threadIdx.x;
  int tot6 = 6*Tp;
  int L = blockIdx.x + 6*(blockIdx.y + Tp*blockIdx.z);
  int xcd = L & 7, slot = L >> 3;
  int b = xcd + ((slot/tot6) << 3);
  int r6 = slot - (slot/tot6)*tot6;
  int t = r6/6, nb6 = r6 - (r6/6)*6;
  int n0 = nb6*128;
  // weight staging with BN fold computed in-block
  for (int i = tid; i < 4096; i += 256){
    int row = i >> 6, k = i & 63;
    int o = row >> 1, isg = row & 1;
    int tap = k >> 5, c = k & 31;
    const float* W = isg ? gWl : fWl;
    Ash[row*FPAD + k] = f2b(W[(o*32+c)*2 + tap] * bnp[c*2]);
  }
  if (tid < 64){
    int o = tid >> 1, isg = tid & 1;
    const float* W = isg ? gWl : fWl;
    const float* B = isg ? gbl : fbl;
    float s = B[o];
    for (int c = 0; c < 32; ++c)
      s += (W[(o*32+c)*2] + W[(o*32+c)*2+1]) * bnp[c*2+1];
    bsh[tid] = s;
  }
  #pragma unroll
  for (int i = 0; i < 8; ++i){
    int idx = tid + i*256;
    int n4 = (idx & 31)*4;
    int cc = idx >> 5;
    int c = cc & 31, tap = cc >> 5;
    long base = ((long)(b*32+c)*T + t + (tap ? d : 0))*NN + n0 + n4;
    ushort4 v = {0,0,0,0};
    if (n0 + n4 < NN) v = *(const ushort4*)(x + base);
    Bsh[(n4+0)*FPAD + cc] = v.x;
    Bsh[(n4+1)*FPAD + cc] = v.y;
    Bsh[(n4+2)*FPAD + cc] = v.z;
    Bsh[(n4+3)*FPAD + cc] = v.w;
  }
  __syncthreads();
  int wave = tid >> 6, lane = tid & 63;
  int lr = lane & 15, lg = lane >> 4;
  int rowbase = wave*16;
  bf16x8 a0 = *(const bf16x8*)&Ash[(rowbase+lr)*FPAD + lg*8];
  bf16x8 a1 = *(const bf16x8*)&Ash[(rowbase+lr)*FPAD + 32 + lg*8];
  float bf0 = bsh[rowbase + lg*4 + 0];
  float bg0 = bsh[rowbase + lg*4 + 1];
  float bf1 = bsh[rowbase + lg*4 + 2];
  float bg1 = bsh[rowbase + lg*4 + 3];
  int o0 = (rowbase >> 1) + lg*2;
  #pragma unroll
  for (int nt = 0; nt < 8; ++nt){
    bf16x8 b0 = *(const bf16x8*)&Bsh[(nt*16+lr)*FPAD + lg*8];
    bf16x8 b1 = *(const bf16x8*)&Bsh[(nt*16+lr)*FPAD + 32 + lg*8];
    f32x4 acc = {};
    acc = __builtin_amdgcn_mfma_f32_16x16x32_bf16(a0, b0, acc, 0,0,0);
    acc = __builtin_amdgcn_mfma_f32_16x16x32_bf16(a1, b1, acc, 0,0,0);
    int n = n0 + nt*16 + lr;
    if (n < NN){
      float f0 = acc[0] + bf0, g0 = acc[1] + bg0;
      float f1 = acc[2] + bf1, g1 = acc[3] + bg1;
      fg[((long)(b*32+o0)*Tp + t)*NN + n]   = f2b(ftanh_(f0)*fsig_(g0));
      fg[((long)(b*32+o0+1)*Tp + t)*NN + n] = f2b(ftanh_(f1)*fsig_(g1));
    }
  }
}

// ---------------- MFMA xg channel-mix: F = oma*(gcb + W0*F + W1*z1 + W2*z2) ----------------
__global__ __launch_bounds__(256) void k_xgmix_mfma(bfu* __restrict__ F,
    const bfu* __restrict__ z1, const bfu* __restrict__ z2,
    const float* __restrict__ Wl, const float* __restrict__ bl,
    const float* __restrict__ alpha, int Tp)
{
  __shared__ bfu Bsh[128*XPAD];
  __shared__ bfu Ash[32*XPAD];
  __shared__ float bsh[32];
  int tid = threadIdx.x;
  int tot6 = 6*Tp;
  int L = blockIdx.x + 6*(blockIdx.y + Tp*blockIdx.z);
  int xcd = L & 7, slot = L >> 3;
  int b = xcd + ((slot/tot6) << 3);
  int r6 = slot - (slot/tot6)*tot6;
  int t = r6/6, nb6 = r6 - (r6/6)*6;
  int n0 = nb6*128;
  // A = Wl rows directly: A[o][k], k-blocks = [W0 c][W1 c][W2 c]
  for (int i = tid; i < 3072; i += 256){
    int o = i/96, k = i - o*96;
    Ash[o*XPAD + k] = f2b(Wl[i]);
  }
  if (tid < 32) bsh[tid] = bl[tid];
  // B rows cc: 0..31 = F channels, 32..63 = z1, 64..95 = z2
  #pragma unroll
  for (int i = 0; i < 12; ++i){
    int idx = tid + i*256;
    int cc = idx % 96;
    int n4 = (idx / 96) * 4;
    const bfu* src = (cc < 32) ? F : ((cc < 64) ? z1 : z2);
    int c = cc & 31;
    long base = ((long)(b*32+c)*Tp + t)*NN + n0 + n4;
    ushort4 v = {0,0,0,0};
    if (n0 + n4 < NN) v = *(const ushort4*)(src + base);
    Bsh[(n4+0)*XPAD + cc] = v.x;
    Bsh[(n4+1)*XPAD + cc] = v.y;
    Bsh[(n4+2)*XPAD + cc] = v.z;
    Bsh[(n4+3)*XPAD + cc] = v.w;
  }
  __syncthreads();
  int wave = tid >> 6, lane = tid & 63;
  int lr = lane & 15, lg = lane >> 4;
  int rt = wave & 1;          // row tile (o 0-15 / 16-31)
  int ntb = wave >> 1;        // n-tile base (0/1), step 2
  bf16x8 a0 = *(const bf16x8*)&Ash[(rt*16+lr)*XPAD + 0  + lg*8];
  bf16x8 a1 = *(const bf16x8*)&Ash[(rt*16+lr)*XPAD + 32 + lg*8];
  bf16x8 a2 = *(const bf16x8*)&Ash[(rt*16+lr)*XPAD + 64 + lg*8];
  float oma = 1.f - sigmoidf_(alpha[0]);
  #pragma unroll
  for (int j = 0; j < 4; ++j){
    int nt = ntb + j*2;
    bf16x8 b0 = *(const bf16x8*)&Bsh[(nt*16+lr)*XPAD + 0  + lg*8];
    bf16x8 b1 = *(const bf16x8*)&Bsh[(nt*16+lr)*XPAD + 32 + lg*8];
    bf16x8 b2 = *(const bf16x8*)&Bsh[(nt*16+lr)*XPAD + 64 + lg*8];
    f32x4 acc = {};
    acc = __builtin_amdgcn_mfma_f32_16x16x32_bf16(a0, b0, acc, 0,0,0);
    acc = __builtin_amdgcn_mfma_f32_16x16x32_bf16(a1, b1, acc, 0,0,0);
    acc = __builtin_amdgcn_mfma_f32_16x16x32_bf16(a2, b2, acc, 0,0,0);
    int n = n0 + nt*16 + lr;
    if (n < NN){
      #pragma unroll
      for (int r = 0; r < 4; ++r){
        int o = rt*16 + lg*4 + r;
        F[((long)(b*32+o)*Tp + t)*NN + n] = f2b(oma*(acc[r] + bsh[o]));
      }
    }
  }
}

// ---------------- pivotal diffusion, fused both orders; 4 m per WAVE (16/block) ----------------
// ApkT [k][r] coalesced scalar loads; each load feeds 4 FMA (ApkT traffic /4)
__global__ __launch_bounds__(256) void k_pgdiff12(const bfu* __restrict__ X,
    float* __restrict__ U1, bfu* __restrict__ Y1k,
    float* __restrict__ U2, bfu* __restrict__ Y2k,
    const int* __restrict__ idxk, const float* __restrict__ uvec,
    const float* __restrict__ ApkT, const float* __restrict__ bnp,
    int M, int Trow, int Tcomp)
{
  __shared__ float xks[16][100];
  __shared__ float yks[16][100];
  int tid = threadIdx.x;
  int g = tid >> 6, lane = tid & 63;
  int m0 = blockIdx.x*16 + g*4;
  float s[4], sk[4];
  #pragma unroll
  for (int j = 0; j < 4; ++j){
    int m = m0 + j;
    s[j] = 0.f; sk[j] = 0.f;
    if (m < M){
      int mrow = (m/Tcomp)*Trow + (m%Tcomp);
      const bfu* xr = X + (long)mrow*NN;
      float ss = 0.f;
      #pragma unroll
      for (int q = 0; q < 12; ++q){
        int v = lane + q*64;
        if (v < NN) ss += b2f(xr[v]);
      }
      for (int o = 32; o; o >>= 1) ss += __shfl_xor(ss, o, 64);
      s[j] = ss;
      float kk = 0.f;
      #pragma unroll
      for (int q = 0; q < 2; ++q){
        int k = lane + q*64;
        if (k < 100){
          float v = b2f(xr[idxk[k]]);
          xks[g*4+j][k] = v;
          kk += v;
        }
      }
      for (int o = 32; o; o >>= 1) kk += __shfl_xor(kk, o, 64);
      sk[j] = kk;
    }
  }
  __syncthreads();
  // per-m BN params + U1
  float sb4[4], bb4[4], u1[4];
  #pragma unroll
  for (int j = 0; j < 4; ++j){
    int m = m0 + j;
    sb4[j] = 1.f; bb4[j] = 0.f; u1[j] = 0.f;
    if (m < M){
      int c = (m / Tcomp) & 31;
      sb4[j] = bnp[c*2]; bb4[j] = bnp[c*2+1];
      u1[j] = sb4[j]*(s[j]*(1.f/716.f)) + bb4[j];
      if (lane == 0) U1[m] = u1[j];
    }
  }
  // matvec 1: Y1 = bn( Apk * xks + u*(s-sk) )
  float sumY[4] = {0,0,0,0};
  #pragma unroll
  for (int q = 0; q < 2; ++q){
    int r = lane + q*64;
    if (r < 100){
      float ur = uvec[r];
      float acc0 = ur*(s[0] - sk[0]);
      float acc1 = ur*(s[1] - sk[1]);
      float acc2 = ur*(s[2] - sk[2]);
      float acc3 = ur*(s[3] - sk[3]);
      for (int k = 0; k < 100; ++k){
        float ap = ApkT[k*100 + r];
        acc0 += ap * xks[g*4+0][k];
        acc1 += ap * xks[g*4+1][k];
        acc2 += ap * xks[g*4+2][k];
        acc3 += ap * xks[g*4+3][k];
      }
      float accs[4] = {acc0, acc1, acc2, acc3};
      #pragma unroll
      for (int j = 0; j < 4; ++j){
        int m = m0 + j;
        if (m < M){
          bfu yv = f2b(sb4[j]*accs[j] + bb4[j]);
          Y1k[(long)m*100 + r] = yv;
          float yf = b2f(yv);
          yks[g*4+j][r] = yf;
          sumY[j] += yf;
        }
      }
    }
  }
  #pragma unroll
  for (int j = 0; j < 4; ++j)
    for (int o = 32; o; o >>= 1) sumY[j] += __shfl_xor(sumY[j], o, 64);
  __syncthreads();
  // U2 + matvec 2: Y2 = Apk * yks + u*base
  float base[4];
  #pragma unroll
  for (int j = 0; j < 4; ++j){
    int m = m0 + j;
    base[j] = 616.f*u1[j];
    if (m < M && lane == 0) U2[m] = (base[j] + sumY[j])*(1.f/716.f);
  }
  #pragma unroll
  for (int q = 0; q < 2; ++q){
    int r = lane + q*64;
    if (r < 100){
      float ur = uvec[r];
      float acc0 = ur*base[0];
      float acc1 = ur*base[1];
      float acc2 = ur*base[2];
      float acc3 = ur*base[3];
      for (int k = 0; k < 100; ++k){
        float ap = ApkT[k*100 + r];
        acc0 += ap * yks[g*4+0][k];
        acc1 += ap * yks[g*4+1][k];
        acc2 += ap * yks[g*4+2][k];
        acc3 += ap * yks[g*4+3][k];
      }
      float accs[4] = {acc0, acc1, acc2, acc3};
      #pragma unroll
      for (int j = 0; j < 4; ++j){
        int m = m0 + j;
        if (m < M) Y2k[(long)m*100 + r] = f2b(accs[j]);
      }
    }
  }
}

// premix
__global__ __launch_bounds__(256) void k_ymix(const float* __restrict__ U1,
    const float* __restrict__ U2, const bfu* __restrict__ Y1k, const bfu* __restrict__ Y2k,
    const float* __restrict__ pWl, float* __restrict__ V12, float* __restrict__ M12, int Tp)
{
  int t = blockIdx.x, b = blockIdx.y, tid = threadIdx.x;
  __shared__ float w1t[1024], w2t[1024];
  __shared__ float y1s[3200], y2s[3200];
  __shared__ float u1s[32], u2s[32];
  for (int i = tid; i < 1024; i += 256){
    int o = i & 31, c = i >> 5;
    w1t[c*32+o] = pWl[o*96+32+c];
    w2t[c*32+o] = pWl[o*96+64+c];
  }
  for (int i = tid; i < 3200; i += 256){
    int c = i/100, r = i - c*100;
    long m = (long)(b*32+c)*Tp + t;
    y1s[i] = b2f(Y1k[m*100 + r]);
    y2s[i] = b2f(Y2k[m*100 + r]);
  }
  if (tid < 32){
    long m = (long)(b*32+tid)*Tp + t;
    u1s[tid] = U1[m]; u2s[tid] = U2[m];
  }
  __syncthreads();
  for (int i = tid; i < 3200; i += 256){
    int r = i >> 5, o = i & 31;
    float acc = 0.f;
    #pragma unroll 8
    for (int c = 0; c < 32; ++c)
      acc += w1t[c*32+o]*y1s[c*100+r] + w2t[c*32+o]*y2s[c*100+r];
    M12[((long)(b*Tp+t)*100 + r)*32 + o] = acc;
  }
  if (tid < 32){
    float acc = 0.f;
    #pragma unroll 8
    for (int c = 0; c < 32; ++c)
      acc += w1t[c*32+tid]*u1s[c] + w2t[c*32+tid]*u2s[c];
    V12[(long)(b*Tp+t)*32 + tid] = acc;
  }
}

// ---------------- combine + skip + fused BN partials; 2 n/thread ----------------
__global__ __launch_bounds__(256) void k_combine3nc(const bfu* __restrict__ x,
    bfu* __restrict__ F, const int* __restrict__ rankv,
    const float* __restrict__ M12, const float* __restrict__ V12,
    const float* __restrict__ pWl, const float* __restrict__ pbl,
    const float* __restrict__ skWl, const float* __restrict__ skbl,
    const float* __restrict__ alpha, const float* __restrict__ bnp,
    bfu* __restrict__ skipP, float* __restrict__ bnred,
    int T, int Tp, int d, int off2)
{
  __shared__ float w0t[1024];
  __shared__ bfu Msb[101*34];      // bf16, stride 34 (bank spread on sel)
  __shared__ float swt[256], bnl[64], pbs[32], sb8[8];
  int tid = threadIdx.x;
  int tot2 = 2*Tp;
  int L = blockIdx.x + 2*(blockIdx.y + Tp*blockIdx.z);
  int xcd = L & 7, slot = L >> 3;
  int b = xcd + ((slot/tot2) << 3);
  int r2 = slot - (slot/tot2)*tot2;
  int t = r2/2, bx2 = r2 & 1;
  for (int i = tid; i < 1024; i += 256){
    int o = i & 31, c = i >> 5;
    w0t[c*32+o] = pWl[o*96+c];
  }
  for (int i = tid; i < 3434; i += 256){
    int r = i/34, o = i - r*34;
    if (o < 32)
      Msb[r*34+o] = f2b((r < 100) ? M12[((long)(b*Tp+t)*100 + r)*32 + o]
                                  : V12[(long)(b*Tp+t)*32 + o]);
  }
  swt[tid] = skWl[tid];
  if (tid < 64) bnl[tid] = bnp[tid];
  if (tid < 32) pbs[tid] = pbl[tid];
  if (tid < 8)  sb8[tid] = skbl[tid];
  __syncthreads();
  int n = bx2*512 + tid*2;
  bool act = (n < NN);
  float ax[32], ay[32];
  #pragma unroll
  for (int o = 0; o < 32; ++o){ ax[o] = pbs[o]; ay[o] = pbs[o]; }
  const float4* w04 = (const float4*)w0t;
  if (act){
    #pragma unroll 2
    for (int c = 0; c < 32; ++c){
      float sc = bnl[c*2], bc = bnl[c*2+1];
      ushort2 xv = *(const ushort2*)(x + ((long)(b*32+c)*T + t)*NN + n);
      float x0 = b2f(xv.x)*sc + bc;
      float x1 = b2f(xv.y)*sc + bc;
      #pragma unroll
      for (int o4 = 0; o4 < 8; ++o4){
        float4 w = w04[c*8+o4];
        ax[o4*4+0] += w.x*x0;  ay[o4*4+0] += w.x*x1;
        ax[o4*4+1] += w.y*x0;  ay[o4*4+1] += w.y*x1;
        ax[o4*4+2] += w.z*x0;  ay[o4*4+2] += w.z*x1;
        ax[o4*4+3] += w.w*x0;  ay[o4*4+3] += w.w*x1;
      }
    }
  }
  int ra = act ? rankv[n]   : -1;
  int rb = act ? rankv[n+1] : -1;
  int sela = (ra < 0) ? 100 : ra;
  int selb = (rb < 0) ? 100 : rb;
  float a_s = sigmoidf_(alpha[0]);
  #pragma unroll
  for (int o = 0; o < 32; ++o){
    float v0 = 0.f, v1 = 0.f;
    if (act){
      float scb = bnl[o*2], bcb = bnl[o*2+1];
      long oidx = ((long)(b*32+o)*Tp + t)*NN + n;
      ushort2 gv = *(const ushort2*)(F + oidx);
      ushort2 rv = *(const ushort2*)(x + ((long)(b*32+o)*T + t + d)*NN + n);
      v0 = a_s*(ax[o] + b2f(Msb[sela*34+o])) + b2f(gv.x) + b2f(rv.x)*scb + bcb;
      v1 = a_s*(ay[o] + b2f(Msb[selb*34+o])) + b2f(gv.y) + b2f(rv.y)*scb + bcb;
      ushort2 ov; ov.x = f2b(v0); ov.y = f2b(v1);
      *(ushort2*)(F + oidx) = ov;
    }
    ax[o] = v0; ay[o] = v1;
  }
  {
    int wave = tid >> 6;
    int gid = ((blockIdx.x + gridDim.x*(blockIdx.y + gridDim.y*blockIdx.z)) << 2) + wave;
    #pragma unroll
    for (int o = 0; o < 32; ++o){
      float v  = ax[o] + ay[o];
      float vq = ax[o]*ax[o] + ay[o]*ay[o];
      for (int s = 32; s; s >>= 1){
        v  += __shfl_xor(v,  s, 64);
        vq += __shfl_xor(vq, s, 64);
      }
      if ((tid & 63) == 0){
        bnred[((long)o*MAXG + gid)*2]     = v;
        bnred[((long)o*MAXG + gid)*2 + 1] = vq;
      }
    }
  }
  if (!act) return;
  const float4* sw4 = (const float4*)swt;
  #pragma unroll
  for (int sc2 = 0; sc2 < 8; ++sc2){
    float s0 = sb8[sc2], s1 = sb8[sc2];
    #pragma unroll
    for (int c4 = 0; c4 < 8; ++c4){
      float4 w = sw4[sc2*8 + c4];
      s0 += w.x*ax[c4*4] + w.y*ax[c4*4+1] + w.z*ax[c4*4+2] + w.w*ax[c4*4+3];
      s1 += w.x*ay[c4*4] + w.y*ay[c4*4+1] + w.z*ay[c4*4+2] + w.w*ay[c4*4+3];
    }
    ushort2 ov; ov.x = f2b(fmaxf(s0, 0.f)); ov.y = f2b(fmaxf(s1, 0.f));
    *(ushort2*)(skipP + ((long)b*416 + off2 + t*8 + sc2)*NN + n) = ov;
  }
}

// reduce per-wave BN partials -> bnp
__global__ void k_bn2v2(const float* __restrict__ red, const float* __restrict__ gamma,
                        const float* __restrict__ beta, float* __restrict__ bnp,
                        int layer, int Tp, int ngroups){
  int c = blockIdx.x, tid = threadIdx.x;
  float s = 0.f, s2 = 0.f;
  for (int g = tid; g < ngroups; g += 256){
    s  += red[((long)c*MAXG + g)*2];
    s2 += red[((long)c*MAXG + g)*2 + 1];
  }
  __shared__ float rs[256], rs2[256];
  rs[tid] = s; rs2[tid] = s2; __syncthreads();
  for (int k = 128; k > 0; k >>= 1){
    if (tid < k){ rs[tid] += rs[tid+k]; rs2[tid] += rs2[tid+k]; }
    __syncthreads();
  }
  if (tid == 0){
    float cnt = 64.f*Tp*716.f;
    float mu = rs[0]/cnt, var = rs2[0]/cnt - mu*mu;
    float rstd = rsqrtf(var + 1e-5f);
    float ga = gamma[layer*32+c], be = beta[layer*32+c];
    bnp[c*2] = rstd*ga; bnp[c*2+1] = be - mu*rstd*ga;
  }
}

// ---------------- end MLP ----------------

__global__ __launch_bounds__(256) void k_sktr(const bfu* __restrict__ SP, bfu* __restrict__ ST){
  __shared__ bfu tile[64][66];
  int b = blockIdx.z;
  int n0 = blockIdx.x*64, k0 = blockIdx.y*64;
  int tid = threadIdx.x;
  int tr = tid >> 6, tc = tid & 63;
  #pragma unroll
  for (int p = 0; p < 16; ++p){
    int k = k0 + p*4 + tr, n = n0 + tc;
    tile[p*4+tr][tc] = (k < 416 && n < NN) ? SP[((long)b*416 + k)*NN + n] : (bfu)0;
  }
  __syncthreads();
  #pragma unroll
  for (int p = 0; p < 16; ++p){
    int n = n0 + p*4 + tr, k = k0 + tc;
    if (n < NN && k < 416) ST[((long)b*NN + n)*416 + k] = tile[tc][p*4+tr];
  }
}

__global__ __launch_bounds__(256) void k_end2(const bfu* __restrict__ H,
    const float* __restrict__ W2, const float* __restrict__ b2, float* __restrict__ out)
{
  __shared__ float w[12*512];
  for (int i = threadIdx.x; i < 6144; i += 256) w[i] = W2[i];
  __syncthreads();
  int n = blockIdx.x*256 + threadIdx.x; if (n >= NN) return;
  int b = blockIdx.y;
  float acc[12];
  #pragma unroll
  for (int o = 0; o < 12; ++o) acc[o] = b2[o];
  for (int e = 0; e < 512; ++e){
    float h = b2f(H[((long)b*512+e)*NN + n]);
    #pragma unroll
    for (int o = 0; o < 12; ++o) acc[o] += w[o*512+e]*h;
  }
  #pragma unroll
  for (int o = 0; o < 12; ++o) out[((long)b*12+o)*NN + n] = acc[o];
}

// ---------------- launch ----------------

extern "C" void kernel_launch(void* const* d_in, const int* in_sizes, int n_in,
                              void* d_out, int out_size, void* d_ws, size_t ws_size,
                              hipStream_t stream)
{
  const float* hist = (const float*)d_in[0];
  const float* alpha = (const float*)d_in[1];
  const float* p1  = (const float*)d_in[2];
  const float* p2  = (const float*)d_in[3];
  const float* p3  = (const float*)d_in[4];
  const float* pk  = (const float*)d_in[5];
  const float* piv = (const float*)d_in[6];
  const float* sW  = (const float*)d_in[7];
  const float* sb  = (const float*)d_in[8];
  const float* saW = (const float*)d_in[9];
  const float* sab = (const float*)d_in[10];
  const float* fW  = (const float*)d_in[11];
  const float* fb  = (const float*)d_in[12];
  const float* gW  = (const float*)d_in[13];
  const float* gb  = (const float*)d_in[14];
  const float* skW = (const float*)d_in[15];
  const float* skb = (const float*)d_in[16];
  const float* gcW = (const float*)d_in[17];
  const float* gcb = (const float*)d_in[18];
  const float* pgW = (const float*)d_in[19];
  const float* pgb = (const float*)d_in[20];
  const float* bng = (const float*)d_in[21];
  const float* bnb = (const float*)d_in[22];
  const float* e1W = (const float*)d_in[23];
  const float* e1b = (const float*)d_in[24];
  const float* e2W = (const float*)d_in[25];
  const float* e2b = (const float*)d_in[26];
  float* out = (float*)d_out;

  char* base = (char*)d_ws;
  size_t off = 0;
  auto alloc = [&](size_t bytes)->char*{
    char* r = base + off;
    off = (off + bytes + 255) & ~(size_t)255;
    return r;
  };
  const size_t SZ12 = 64UL*32*12*716*2;
  const size_t SZ13 = 64UL*32*13*716*2;
  bfu*   t1    = (bfu*)  alloc(SZ12);
  bfu*   t2    = (bfu*)  alloc(SZ12);
  bfu*   P     = (bfu*)  alloc(SZ13);
  bfu*   Q     = (bfu*)  alloc(SZ12);
  bfu*   skipP = (bfu*)  alloc(64UL*416*716*2);
  bfu*   skipT = (bfu*)  alloc(64UL*716*416*2);
  float* adjp  = (float*)alloc((size_t)NSQ*4);
  float* tmp1  = (float*)alloc(64UL*1600*4);
  float* tmp2  = (float*)alloc(64UL*716*40*4);
  float* p3t   = (float*)alloc(40UL*716*4);
  bfu*   e1Wb  = (bfu*)  alloc(512UL*416*2);
  unsigned int* topA = (unsigned int*)alloc(64UL*NN*16*4);
  int*   cntA  = (int*)  alloc(64UL*NN*4);
  float* xs    = (float*)alloc(716UL*13*4);
  float* yv    = (float*)alloc(716UL*4);
  float* score = (float*)alloc(716UL*4);
  float* bnred = (float*)alloc(32UL*MAXG*2*4);
  float* bnp   = (float*)alloc(64UL*4);
  float* bnpid = (float*)alloc(64UL*4);
  float* uvec  = (float*)alloc(100UL*4);
  float* ApkT  = (float*)alloc(100UL*100*4);
  int*   ind   = (int*)  alloc(64UL*4);
  int*   mask  = (int*)  alloc(716UL*4);
  int*   idxk  = (int*)  alloc(100UL*4);
  int*   rankv = (int*)  alloc(716UL*4);

  // pgcn-compact buffers aliased INTO t1 (dead between k_xgmix_mfma and next gather)
  char* t1c = (char*)t1;
  float* U1  = (float*)(t1c);
  float* U2  = (float*)(t1c +   98304);
  float* V12 = (float*)(t1c + 2*98304);
  float* M12 = (float*)(t1c + 3*98304);
  bfu*   Y1k = (bfu*)  (t1c + 3*98304 + 9830400);
  bfu*   Y2k = (bfu*)  (t1c + 3*98304 + 9830400 + 4915200);

  bfu* hidden = t1;

  // dynamic adjacency (sparse capture)
  k_ind<<<1,64,0,stream>>>(hist, ind);
  k_dg1<<<64,256,0,stream>>>(p1, pk, ind, tmp1);
  k_dg2<<<dim3(112,64),256,0,stream>>>(p2, tmp1, tmp2);
  k_p3t<<<3,256,0,stream>>>(p3, p3t);
  k_adjrow4s<<<dim3(179,64),256,0,stream>>>(p3t, tmp2, topA, cntA);
  // pivotal adjacency (compact structure)
  k_xs<<<716,64,0,stream>>>(hist, saW, sab, xs, yv);
  k_adjp<<<dim3(3,716),256,0,stream>>>(xs, yv, piv, adjp);
  k_score<<<716,256,0,stream>>>(adjp, score);
  k_topk<<<1,256,0,stream>>>(score, mask);
  k_pivprep<<<1,256,0,stream>>>(adjp, mask, idxk, rankv, uvec, ApkT);
  // start conv + weight conversion + identity BN
  k_init_x<<<dim3(3,13,64),256,0,stream>>>(hist, sW, sb, P);
  k_e1perm<<<(512*416+255)/256,256,0,stream>>>(e1W, e1Wb);
  k_bnid<<<1,64,0,stream>>>(bnpid);

  int T = 13;
  bfu* x = P;
  bfu* F = Q;
  static const int off2_[8] = {0,96,176,248,304,352,384,408};
  for (int i = 0; i < 8; ++i){
    int d = (i & 1) ? 2 : 1;
    int Tp = T - d;
    const float* bnin = (i == 0) ? bnpid : bnp;
    dim3 g2n(2, Tp, 64);
    dim3 g6(6, Tp, 64);
    // MFMA gated conv, BN folded in-block
    k_fg_mfma<<<g6,256,0,stream>>>(x, fW + i*2048, fb + i*32, gW + i*2048, gb + i*32,
        bnin, F, T, Tp, d);
    // xg path: fused double sparse diffusion then MFMA channel-mix over F
    int M1 = 32*Tp; long sx1 = (long)M1*NN;
    dim3 gz((M1+3)/4, 64);
    k_zgather2<<<gz,256,0,stream>>>(F, topA, cntA, t1, t2, M1, sx1);
    k_xgmix_mfma<<<g6,256,0,stream>>>(F, t1, t2, gcW + i*3072, gcb + i*32, alpha, Tp);
    // pgcn path, compact (fused 1st+2nd diffusion; 16 m per block, 4 per wave)
    int M2 = 64*32*Tp;
    k_pgdiff12<<<(M2+15)/16,256,0,stream>>>(x, U1, Y1k, U2, Y2k, idxk, uvec, ApkT, bnin,
        M2, T, Tp);
    k_ymix<<<dim3(Tp,64),256,0,stream>>>(U1, U2, Y1k, Y2k, pgW + i*3072, V12, M12, Tp);
    // combine + residual + skip + fused BN partials (2 n/thread)
    k_combine3nc<<<g2n,256,0,stream>>>(x, F, rankv, M12, V12, pgW + i*3072, pgb + i*32,
        skW + i*256, skb + i*8, alpha, bnin, skipP, bnred, T, Tp, d, off2_[i]);
    int ngroups = 2*Tp*64*4;
    k_bn2v2<<<32,256,0,stream>>>(bnred, bng, bnb, bnp, i, Tp, ngroups);
    bfu* tmp = x; x = F; F = tmp;
    T = Tp;
  }
  // end MLP
  k_sktr<<<dim3(12,7,64),256,0,stream>>>(skipP, skipT);
  gemm_mfma<<<dim3(6,4,64),256,0,stream>>>(e1Wb, skipT, hidden, 512, 416,
      0L, 416L*716, 512L*716, e1b, 1, 1, 1);
  k_end2<<<dim3(3,64),256,0,stream>>>(hidden, e2W, e2b, out);
}